// Round 10
// baseline (7699.670 us; speedup 1.0000x reference)
//
#include <hip/hip_runtime.h>

typedef unsigned short u16;
typedef __bf16 bf16_t;
typedef long long i64;

#define NN   21
#define BB   256
#define HID  512
#define G3   1536
#define NC2  2048
#define A0S  352
#define PH   12
#define WSK  516   // LDS row stride for naive gemm W tile (floats)

__device__ __forceinline__ u16 f2b(float f){ bf16_t b = (bf16_t)f; return __builtin_bit_cast(u16, b); }
__device__ __forceinline__ float b2f(u16 u){ bf16_t b = __builtin_bit_cast(bf16_t, u); return (float)b; }
__device__ __forceinline__ float sigm(float x){ return 1.0f / (1.0f + __expf(-x)); }
__device__ __forceinline__ float ftanh(float x){
  x = fminf(15.0f, fmaxf(-15.0f, x));
  float e = __expf(2.0f * x);
  return (e - 1.0f) / (e + 1.0f);
}
// dtype-flexible input load. mode: 0 = f32 wire, 1 = f64 wire, 2 = bf16 wire
__device__ __forceinline__ float ldf(const void* p, size_t idx, int mode){
  if (mode == 2) return b2f(((const u16*)p)[idx]);
  if (mode == 1) return (float)((const double*)p)[idx];
  return ((const float*)p)[idx];
}

// ---------------- diagnostics ----------------
__global__ void k_fill(float* out, int n, float c){
  int idx = blockIdx.x*256 + threadIdx.x;
  if (idx < n) out[idx] = c;
}

// ---------------- dtype detection ----------------
// flags[0] = float wire mode (0=f32, 1=f64, 2=bf16); flags[1] = int64 wire?
__global__ void k_detect(const void* w0raw, const void* traw, int* flags){
  if (threadIdx.x != 0 || blockIdx.x != 0) return;
  const float*  v32 = (const float*)w0raw;
  const double* v64 = (const double*)w0raw;
  const u16*    vbf = (const u16*)w0raw;
  int c32 = 0, c64 = 0, cbf = 0;
  for (int i = 0; i < 64; ++i){
    float a32 = fabsf(v32[i]);
    if (a32 >= 1e-8f && a32 <= 1e4f) ++c32;
    double a64 = fabs(v64[i]);
    if (a64 >= 1e-8 && a64 <= 1e4) ++c64;
    float abf = fabsf(b2f(vbf[i]));
    if (abf >= 1e-8f && abf <= 1e4f) ++cbf;
  }
  int mode;
  if (cbf >= 60 && c32 < 48) mode = 2;
  else if (c32 >= 48)        mode = 0;
  else if (c64 >= 48)        mode = 1;
  else                       mode = 2;
  flags[0] = mode;
  const int* tw = (const int*)traw;
  int ok64 = 1;
  for (int i = 0; i < NN; ++i){
    unsigned lo = (unsigned)tw[2*i];
    int hi = tw[2*i+1];
    if (hi != 0 || lo >= 4u) { ok64 = 0; break; }
  }
  flags[1] = ok64;
}
__global__ void k_cvt_i(const void* src, int* dst, int n, const int* flags){
  int idx = threadIdx.x;
  if (idx >= n) return;
  if (flags[1]) dst[idx] = (int)((const i64*)src)[idx];
  else          dst[idx] = ((const int*)src)[idx];
}

// ---------------- prep ----------------
__global__ void k_prep_G(const void* G0, const void* Grnn, const void* GA,
                         const void* Gq, const void* Gc, const int* flags,
                         float* G0s, float* Gns, float* Gqs, float* Gcs){
  int tid = threadIdx.x;
  if (tid >= 84) return;
  const int md = flags[0];
  int mat = tid / 21, row = tid % 21;
  const void* src = mat==0 ? G0 : mat==1 ? Grnn : mat==2 ? Gq : Gc;
  float* dst      = mat==0 ? G0s : mat==1 ? Gns : mat==2 ? Gqs : Gcs;
  float s = 0.f;
  for (int m=0;m<21;++m) s += fabsf(ldf(src,row*21+m,md));
  s = fmaxf(s, 1e-12f);
  for (int m=0;m<21;++m){
    float v = ldf(src,row*21+m,md) / s;
    if (mat==1) v += ldf(GA,row*21+m,md);
    dst[row*21+m] = v;
  }
}

// Axin[n][b][k] f32 (pad 352): [x_{t-1}(8), z(64), h_in(256), 0...]
__global__ void k_build_A0(const void* x, const void* z, const void* hin,
                           const int* flags, float* A0){
  int idx = blockIdx.x*256 + threadIdx.x;
  if (idx >= NN*BB*A0S) return;
  const int md = flags[0];
  int k  = idx % A0S;
  int nb = idx / A0S;
  int b  = nb % BB;
  int n  = nb / BB;
  float v = 0.f;
  if (k < 8)        v = ldf(x, ((size_t)(b*2 + 0)*NN + n)*8 + k, md);
  else if (k < 72)  v = ldf(z, ((size_t)b*NN + n)*64 + (k - 8), md);
  else if (k < 328) v = ldf(hin, ((size_t)b*NN + n)*256 + (k - 72), md);
  A0[idx] = v;
}

// x-cols of Axin -> x_t; init q; emit x_t output (f32)
__global__ void k_init_state(const void* x, const void* qt, const int* flags,
                             float* Axin, float* qc, float* out2){
  int b = threadIdx.x; int n = blockIdx.x;
  const int md = flags[0];
  for (int f=0; f<8; ++f){
    float raw = ldf(x, ((size_t)(b*2 + 1)*NN + n)*8 + f, md);
    Axin[(size_t)(n*BB + b)*A0S + f] = raw;
    out2[(b*NN + n)*8 + f] = raw;
  }
  for (int c=0; c<4; ++c) qc[(n*BB + b)*4 + c] = ldf(qt, ((size_t)b*NN + n)*4 + c, md);
}

// ---------------- naive GEMM (dtype-flexible W/bias) ----------------
// C[n][b][dst(g)] = bias[n][g] (+C existing for GRUH g<1024) + sum_k A[n][b][k]*W[T[n]][g][k]
// GRUH: g<1024 -> dst=g accumulate; g>=1024 -> dst=g+512 fresh.
template<int ABF, int CBF, int GRUH>
__global__ __launch_bounds__(256)
void k_ngemm(const void* __restrict__ A_, int sA,
             const void* __restrict__ W_, int sW, size_t tstride,
             const void* __restrict__ bias_, int biasN,
             const int* __restrict__ T, const int* __restrict__ flags, int K,
             void* __restrict__ C_, int Nc, int goff)
{
  __shared__ float Ws[8*WSK];
  const int node = blockIdx.y;
  const int g0   = blockIdx.x*8;
  const int tid  = threadIdx.x;
  const int t    = T[node];
  const int md   = flags[0];

  for (int idx = tid; idx < 8*K; idx += 256){
    int gg = idx / K, kk = idx - gg*K;
    Ws[gg*WSK + kk] = ldf(W_, (size_t)t*tstride + (size_t)(g0+gg)*sW + kk, md);
  }
  __syncthreads();

  const int b = tid;
  const float* Af = (const float*)A_;
  const u16*   Ab = (const u16*)A_;
  float* Cf = (float*)C_;
  u16*   Cb = (u16*)C_;

  float acc[8];
  int   dst[8];
  #pragma unroll
  for (int gg=0; gg<8; ++gg){
    const int g = g0 + gg;
    float bv = ldf(bias_, (size_t)node*biasN + g, md);
    if (GRUH){
      dst[gg] = (g < 1024) ? g : g + 512;
      if (g < 1024) bv += b2f(Cb[(size_t)(node*BB + b)*Nc + dst[gg]]);
    } else {
      dst[gg] = g + goff;
    }
    acc[gg] = bv;
  }

  const size_t abase = (size_t)(node*BB + b)*sA;
  for (int k=0; k<K; ++k){
    const float av = ABF ? b2f(Ab[abase + k]) : Af[abase + k];
    #pragma unroll
    for (int gg=0; gg<8; ++gg) acc[gg] += av * Ws[gg*WSK + k];
  }

  #pragma unroll
  for (int gg=0; gg<8; ++gg){
    const size_t ci = (size_t)(node*BB + b)*Nc + dst[gg];
    if (CBF) Cb[ci] = f2b(acc[gg]);
    else     Cf[ci] = acc[gg];
  }
}

// ---------------- mixing / GRU / head ----------------

// NOTE: C0 and h may alias (safe: each thread reads all m before writing)
__global__ __launch_bounds__(256)
void k_mix_init(const float* C0, const float* G0s, float* h){
  __shared__ float Gs[441];
  const int tid = threadIdx.x;
  for (int i = tid; i < 441; i += 256) Gs[i] = G0s[i];
  __syncthreads();
  const int b = blockIdx.y;
  const int j = blockIdx.x*256 + tid;
  float P[21];
  #pragma unroll
  for (int m=0;m<21;++m) P[m] = C0[(size_t)(m*BB + b)*HID + j];
  float R[21];
  for (int n=0;n<21;++n){
    float s = 0.f;
    #pragma unroll
    for (int m=0;m<21;++m) s += Gs[n*21+m]*P[m];
    R[n] = s;
  }
  for (int n=0;n<21;++n) h[(size_t)(n*BB + b)*HID + j] = R[n];
}

// Cbig bf16 channels: [0:1024)=xr1+hr1(+biases), [1024:1536)=ic, [1536:2048)=hc2
__global__ __launch_bounds__(256)
void k_gru(const u16* __restrict__ Cb, const float* __restrict__ Gns,
           float* __restrict__ h, u16* __restrict__ y){
  __shared__ float Gs[441];
  const int tid = threadIdx.x;
  for (int i = tid; i < 441; i += 256) Gs[i] = Gns[i];
  __syncthreads();
  const int b = blockIdx.y;
  const int j = blockIdx.x*256 + tid;
  float P1[21], P2[21], P3[21], P4[21];
  #pragma unroll
  for (int m=0;m<21;++m){
    const size_t base = (size_t)(m*BB + b)*NC2 + j;
    P1[m] = b2f(Cb[base]);
    P2[m] = b2f(Cb[base + 512]);
    P3[m] = b2f(Cb[base + 1024]);
    P4[m] = b2f(Cb[base + 1536]);
  }
  for (int n=0;n<21;++n){
    float s1=0.f, s2=0.f, s3=0.f, s4=0.f;
    #pragma unroll
    for (int m=0;m<21;++m){
      const float g = Gs[n*21+m];
      s1 += g*P1[m]; s2 += g*P2[m]; s3 += g*P3[m]; s4 += g*P4[m];
    }
    const size_t hi = (size_t)(n*BB + b)*HID + j;
    const float hc = h[hi];
    const float r  = sigm(s1);
    const float zg = sigm(s2);
    const float nn = ftanh(s3 + r*s4);
    const float hn = (1.f - zg)*nn + zg*hc;
    h[hi] = hn;
    y[hi] = f2b(ftanh(hn));
  }
}

__global__ __launch_bounds__(256)
void k_out(const float* __restrict__ Cqc, const float* __restrict__ Gqs, const float* __restrict__ Gcs,
           const int* __restrict__ T, const int* __restrict__ flags,
           const void* __restrict__ W3, const void* __restrict__ b3,
           const void* __restrict__ W6, const void* __restrict__ b6,
           float* __restrict__ qc, float* __restrict__ Axin,
           float* __restrict__ out_dq, float* __restrict__ out_cov, int s)
{
  const int tid = threadIdx.x;
  const int w = blockIdx.x*4 + (tid >> 6);
  const int lane = tid & 63;
  const int b = w / 21, n = w % 21;
  const int t = T[n];
  const int md = flags[0];
  float aq1=0.f, aq2=0.f, ac1=0.f, ac2=0.f;
  #pragma unroll
  for (int m=0;m<21;++m){
    const float* c = Cqc + (size_t)(m*BB + b)*256;
    const float gq = Gqs[n*21+m], gc = Gcs[n*21+m];
    aq1 += gq*c[lane];       aq2 += gq*c[lane+64];
    ac1 += gc*c[lane+128];   ac2 += gc*c[lane+192];
  }
  const float ys1 = ftanh(aq1), ys2 = ftanh(aq2);
  const float yc1 = ftanh(ac1), yc2 = ftanh(ac2);
  float red[9];
  #pragma unroll
  for (int a=0;a<3;++a)
    red[a] = ys1*ldf(W3,(size_t)(t*3+a)*128 + lane,md) + ys2*ldf(W3,(size_t)(t*3+a)*128 + lane + 64,md);
  #pragma unroll
  for (int a=0;a<6;++a)
    red[3+a] = yc1*ldf(W6,(size_t)(t*6+a)*128 + lane,md) + yc2*ldf(W6,(size_t)(t*6+a)*128 + lane + 64,md);
  #pragma unroll
  for (int i=0;i<9;++i){
    red[i] += __shfl_xor(red[i], 32);
    red[i] += __shfl_xor(red[i], 16);
    red[i] += __shfl_xor(red[i], 8);
    red[i] += __shfl_xor(red[i], 4);
    red[i] += __shfl_xor(red[i], 2);
    red[i] += __shfl_xor(red[i], 1);
  }
  const float d0 = red[0] + ldf(b3,(size_t)n*3+0,md);
  const float d1 = red[1] + ldf(b3,(size_t)n*3+1,md);
  const float d2 = red[2] + ldf(b3,(size_t)n*3+2,md);
  const float theta = sqrtf(d0*d0 + d1*d1 + d2*d2);
  const float wq = cosf(0.5f*theta);
  const float kq = (theta > 1e-8f) ? (sinf(0.5f*theta) / fmaxf(theta, 1e-8f)) : 0.5f;
  const float x1 = kq*d0, y1 = kq*d1, z1 = kq*d2;
  if (lane == 0){
    float* q = qc + (size_t)(n*BB + b)*4;
    const float qw=q[0], qx=q[1], qy=q[2], qz=q[3];
    const float nw = wq*qw - (x1*qx + y1*qy + z1*qz);
    const float nx = wq*qx + qw*x1 + (y1*qz - z1*qy);
    const float ny = wq*qy + qw*y1 + (z1*qx - x1*qz);
    const float nz = wq*qz + qw*z1 + (x1*qy - y1*qx);
    q[0]=nw; q[1]=nx; q[2]=ny; q[3]=nz;
    float* ax = Axin + (size_t)(n*BB + b)*A0S;
    ax[0]=nw; ax[1]=nx; ax[2]=ny; ax[3]=nz;
    ax[4]=wq; ax[5]=x1; ax[6]=y1; ax[7]=z1;
    float* od = out_dq + (size_t)((b*PH + s)*NN + n)*4;
    od[0]=wq; od[1]=x1; od[2]=y1; od[3]=z1;
    float* oc = out_cov + (size_t)((b*PH + s)*NN + n)*6;
    for (int a=0;a<6;++a) oc[a] = red[3+a] + ldf(b6,(size_t)n*6+a,md);
  }
}

// ---------------- launch ----------------

extern "C" void kernel_launch(void* const* d_in, const int* in_sizes, int n_in,
                              void* d_out, int out_size, void* d_ws, size_t ws_size,
                              hipStream_t stream)
{
  const void* P[25];
  {
    int j = 0;
    for (int i = 0; i < 25; ++i){
      if (i == 5){ P[i] = nullptr; continue; }
      while (j < n_in && in_sizes[j] == 1) ++j;
      P[i] = (j < n_in) ? d_in[j++] : nullptr;
    }
  }

  char* wsb = (char*)d_ws;
  size_t off = 0;
  auto carve = [&](size_t bytes)->void*{
    void* p = wsb + off;
    off = (off + bytes + 255) & ~(size_t)255;
    return p;
  };

  int*   flags = (int*)  carve(2*4);
  int*   TI    = (int*)  carve(NN*4);
  float* G0s   = (float*)carve(441*4);
  float* Gns   = (float*)carve(441*4);
  float* Gqs   = (float*)carve(441*4);
  float* Gcs   = (float*)carve(441*4);
  float* Axin  = (float*)carve((size_t)NN*BB*A0S*4);
  float* hbuf  = (float*)carve((size_t)NN*BB*HID*4);
  u16*   Cbig  = (u16*)  carve((size_t)NN*BB*NC2*2);
  u16*   ybuf  = (u16*)  carve((size_t)NN*BB*HID*2);
  float* CqcB  = (float*)carve((size_t)NN*BB*256*4);
  float* qcv   = (float*)carve((size_t)NN*BB*4*4);
  const size_t NEED = off;

  // OUTPUTS ARE FLOAT32 (reference returns float32; harness allocates
  // out_size f32 elements). This was the 8-round bug: bf16 stores read as f32.
  float* out_dq  = (float*)d_out;
  float* out_cov = out_dq  + (size_t)BB*PH*NN*4;
  float* out_xt  = out_cov + (size_t)BB*PH*NN*6;

  if (ws_size < NEED){
    float code = 150.0f + (float)(ws_size >> 23);
    k_fill<<<(out_size+255)/256,256,0,stream>>>((float*)d_out, out_size, code);
    return;
  }

  k_detect<<<1,64,0,stream>>>(P[6], P[4], flags);
  k_cvt_i<<<1,64,0,stream>>>(P[4], TI, NN, flags);

  k_prep_G<<<1,128,0,stream>>>(P[8],P[13],P[14],P[17],P[20],flags, G0s,Gns,Gqs,Gcs);
  k_build_A0<<<(NN*BB*A0S+255)/256,256,0,stream>>>(P[0],P[2],P[1],flags,Axin);

  // rnn_h pre-mix: hbuf = Axin(x_{t-1}) . W0^T + b0
  k_ngemm<0,0,0><<<dim3(HID/8,NN),256,0,stream>>>(Axin,A0S, P[6],328,(size_t)512*328,
      P[7],512, TI,flags, 328, hbuf,512, 0);
  k_mix_init<<<dim3(2,BB),256,0,stream>>>(hbuf,G0s,hbuf);
  k_init_state<<<NN,256,0,stream>>>(P[0],P[3],flags,Axin,qcv,out_xt);

  for (int s=0; s<PH; ++s){
    // xr gates: Cbig[0:1536) = Axin . Wih^T + bih
    k_ngemm<0,1,0><<<dim3(G3/8,NN),256,0,stream>>>(Axin,A0S, P[9],328,(size_t)G3*328,
        P[11],G3, TI,flags, 328, Cbig,NC2, 0);
    // hr gates: Cbig[0:1024) += h.Whh^T[0:1024)+bhh ; Cbig[1536:2048) = h.Whh^T[1024:1536)+bhh
    k_ngemm<0,1,1><<<dim3(G3/8,NN),256,0,stream>>>(hbuf,HID, P[10],512,(size_t)G3*512,
        P[12],G3, TI,flags, 512, Cbig,NC2, 0);
    k_gru<<<dim3(2,BB),256,0,stream>>>(Cbig,Gns,hbuf,ybuf);
    // head: CqcB[0:128)=y.Wq^T+bq ; [128:256)=y.Wc^T+bc
    k_ngemm<1,0,0><<<dim3(128/8,NN),256,0,stream>>>(ybuf,HID, P[15],512,(size_t)128*512,
        P[16],128, TI,flags, 512, CqcB,256, 0);
    k_ngemm<1,0,0><<<dim3(128/8,NN),256,0,stream>>>(ybuf,HID, P[18],512,(size_t)128*512,
        P[19],128, TI,flags, 512, CqcB,256, 128);
    k_out<<<(NN*BB)/4,256,0,stream>>>(CqcB,Gqs,Gcs,TI,flags,P[21],P[22],P[23],P[24],
        qcv,Axin,out_dq,out_cov,s);
  }
}

// Round 11
// 1339.318 us; speedup vs baseline: 5.7489x; 5.7489x over previous
//
#include <hip/hip_runtime.h>

typedef unsigned short u16;
typedef __bf16 bf16_t;
typedef bf16_t bf16x8 __attribute__((ext_vector_type(8)));
typedef float f32x4 __attribute__((ext_vector_type(4)));
typedef long long i64;

#define NN   21
#define BB   256
#define HID  512
#define G3   1536
#define NC2  2048
#define A0S  352
#define PH   12
#define WSK  516
#define LK   40    // LDS row stride (32+8 pad) bf16 elems

__device__ __forceinline__ u16 f2b(float f){ bf16_t b = (bf16_t)f; return __builtin_bit_cast(u16, b); }
__device__ __forceinline__ float b2f(u16 u){ bf16_t b = __builtin_bit_cast(bf16_t, u); return (float)b; }
__device__ __forceinline__ bf16_t fb(float f){ return (bf16_t)f; }
__device__ __forceinline__ float sigm(float x){ return 1.0f / (1.0f + __expf(-x)); }
__device__ __forceinline__ float ftanh(float x){
  x = fminf(15.0f, fmaxf(-15.0f, x));
  float e = __expf(2.0f * x);
  return (e - 1.0f) / (e + 1.0f);
}
// input load. mode: 0=f32 wire, 1=f64, 2=bf16
__device__ __forceinline__ float ldf(const void* p, size_t idx, int mode){
  if (mode == 2) return b2f(((const u16*)p)[idx]);
  if (mode == 1) return (float)((const double*)p)[idx];
  return ((const float*)p)[idx];
}

__global__ void k_fill(float* out, int n, float c){
  int idx = blockIdx.x*256 + threadIdx.x;
  if (idx < n) out[idx] = c;
}

__global__ void k_detect(const void* w0raw, const void* traw, int* flags){
  if (threadIdx.x != 0 || blockIdx.x != 0) return;
  const float*  v32 = (const float*)w0raw;
  const double* v64 = (const double*)w0raw;
  const u16*    vbf = (const u16*)w0raw;
  int c32 = 0, c64 = 0, cbf = 0;
  for (int i = 0; i < 64; ++i){
    float a32 = fabsf(v32[i]);
    if (a32 >= 1e-8f && a32 <= 1e4f) ++c32;
    double a64 = fabs(v64[i]);
    if (a64 >= 1e-8 && a64 <= 1e4) ++c64;
    float abf = fabsf(b2f(vbf[i]));
    if (abf >= 1e-8f && abf <= 1e4f) ++cbf;
  }
  int mode;
  if (cbf >= 60 && c32 < 48) mode = 2;
  else if (c32 >= 48)        mode = 0;
  else if (c64 >= 48)        mode = 1;
  else                       mode = 2;
  flags[0] = mode;
  const int* tw = (const int*)traw;
  int ok64 = 1;
  for (int i = 0; i < NN; ++i){
    unsigned lo = (unsigned)tw[2*i];
    int hi = tw[2*i+1];
    if (hi != 0 || lo >= 4u) { ok64 = 0; break; }
  }
  flags[1] = ok64;
}
__global__ void k_cvt_i(const void* src, int* dst, int n, const int* flags){
  int idx = threadIdx.x;
  if (idx >= n) return;
  if (flags[1]) dst[idx] = (int)((const i64*)src)[idx];
  else          dst[idx] = ((const int*)src)[idx];
}
__global__ void k_cvt_f(const void* src, float* dst, int n, const int* flags){
  int idx = blockIdx.x*256 + threadIdx.x;
  if (idx < n) dst[idx] = ldf(src, idx, flags[0]);
}
// Wih -> bf16 padded to 352 (zeros in [328,352))
__global__ void k_cvt_wpad(const void* W, u16* dst, const int* flags){
  int idx = blockIdx.x*256 + threadIdx.x;
  if (idx >= 4*G3*A0S) return;
  int k = idx % A0S, tg = idx / A0S;
  dst[idx] = (k < 328) ? f2b(ldf(W, (size_t)tg*328 + k, flags[0])) : (u16)0;
}
__global__ void k_cvt_w(const void* W, u16* dst, int n, const int* flags){
  int idx = blockIdx.x*256 + threadIdx.x;
  if (idx < n) dst[idx] = f2b(ldf(W, idx, flags[0]));
}
// Wqc[t][g][k] bf16: g<128 -> Wq, else Wc
__global__ void k_cvt_wqc(const void* Wq, const void* Wc, u16* dst, const int* flags){
  int idx = blockIdx.x*256 + threadIdx.x;
  if (idx >= 4*256*512) return;
  int k  = idx & 511;
  int tg = idx >> 9;
  int g  = tg & 255;
  int t  = tg >> 8;
  const int md = flags[0];
  dst[idx] = f2b((g < 128) ? ldf(Wq, ((size_t)(t*128 + g) << 9) + k, md)
                           : ldf(Wc, ((size_t)(t*128 + (g-128)) << 9) + k, md));
}
__global__ void k_bqc(const void* bq, const void* bc, float* bqc, const int* flags){
  int idx = blockIdx.x*256 + threadIdx.x;
  if (idx >= NN*256) return;
  int o = idx & 255; int n = idx >> 8;
  const int md = flags[0];
  bqc[idx] = (o < 128) ? ldf(bq,(size_t)n*128+o,md) : ldf(bc,(size_t)n*128+(o-128),md);
}

__global__ void k_prep_G(const void* G0, const void* Grnn, const void* GA,
                         const void* Gq, const void* Gc, const int* flags,
                         float* G0s, float* Gns, float* Gqs, float* Gcs){
  int tid = threadIdx.x;
  if (tid >= 84) return;
  const int md = flags[0];
  int mat = tid / 21, row = tid % 21;
  const void* src = mat==0 ? G0 : mat==1 ? Grnn : mat==2 ? Gq : Gc;
  float* dst      = mat==0 ? G0s : mat==1 ? Gns : mat==2 ? Gqs : Gcs;
  float s = 0.f;
  for (int m=0;m<21;++m) s += fabsf(ldf(src,row*21+m,md));
  s = fmaxf(s, 1e-12f);
  for (int m=0;m<21;++m){
    float v = ldf(src,row*21+m,md) / s;
    if (mat==1) v += ldf(GA,row*21+m,md);
    dst[row*21+m] = v;
  }
}

// Axin bf16 [n][b][352]: [x(8), z(64), h_in(256), 0 pad]
__global__ void k_build_A0(const void* x, const void* z, const void* hin,
                           const int* flags, u16* A0){
  int idx = blockIdx.x*256 + threadIdx.x;
  if (idx >= NN*BB*A0S) return;
  const int md = flags[0];
  int k  = idx % A0S;
  int nb = idx / A0S;
  int b  = nb % BB;
  int n  = nb / BB;
  float v = 0.f;
  if (k < 8)        v = ldf(x, ((size_t)(b*2 + 0)*NN + n)*8 + k, md);
  else if (k < 72)  v = ldf(z, ((size_t)b*NN + n)*64 + (k - 8), md);
  else if (k < 328) v = ldf(hin, ((size_t)b*NN + n)*256 + (k - 72), md);
  A0[idx] = f2b(v);
}

__global__ void k_init_state(const void* x, const void* qt, const int* flags,
                             u16* Axin, float* qc, float* out2){
  int b = threadIdx.x; int n = blockIdx.x;
  const int md = flags[0];
  for (int f=0; f<8; ++f){
    float raw = ldf(x, ((size_t)(b*2 + 1)*NN + n)*8 + f, md);
    Axin[(size_t)(n*BB + b)*A0S + f] = f2b(raw);
    out2[(b*NN + n)*8 + f] = raw;
  }
  for (int c=0; c<4; ++c) qc[(n*BB + b)*4 + c] = ldf(qt, ((size_t)b*NN + n)*4 + c, md);
}

// ---------------- naive GEMM (init W0 only) ----------------
template<int ABF>
__global__ __launch_bounds__(256)
void k_ngemm(const void* __restrict__ A_, int sA,
             const void* __restrict__ W_, int sW, size_t tstride,
             const void* __restrict__ bias_, int biasN,
             const int* __restrict__ T, const int* __restrict__ flags, int K,
             float* __restrict__ C, int Nc)
{
  __shared__ float Ws[8*WSK];
  const int node = blockIdx.y;
  const int g0   = blockIdx.x*8;
  const int tid  = threadIdx.x;
  const int t    = T[node];
  const int md   = flags[0];
  for (int idx = tid; idx < 8*K; idx += 256){
    int gg = idx / K, kk = idx - gg*K;
    Ws[gg*WSK + kk] = ldf(W_, (size_t)t*tstride + (size_t)(g0+gg)*sW + kk, md);
  }
  __syncthreads();
  const int b = tid;
  const float* Af = (const float*)A_;
  const u16*   Ab = (const u16*)A_;
  float acc[8];
  #pragma unroll
  for (int gg=0; gg<8; ++gg) acc[gg] = ldf(bias_, (size_t)node*biasN + g0 + gg, md);
  const size_t abase = (size_t)(node*BB + b)*sA;
  for (int k=0; k<K; ++k){
    const float av = ABF ? b2f(Ab[abase + k]) : Af[abase + k];
    #pragma unroll
    for (int gg=0; gg<8; ++gg) acc[gg] += av * Ws[gg*WSK + k];
  }
  #pragma unroll
  for (int gg=0; gg<8; ++gg)
    C[(size_t)(node*BB + b)*Nc + g0 + gg] = acc[gg];
}

// ---------------- MFMA GEMM ----------------
// C[n][b][dstcol] = bias[n][col] (+Cprev for GRUH ntile<8) + sum_k A[n][b][k]*W[T[n]][col][k]
// AMODE 0: A bf16 stride sA. AMODE 1: A fp32 stride sA (converted in staging).
// GRUH: ntile<8 -> dstcol=col, accumulate onto C; ntile>=8 -> dstcol=col+512 fresh.
// C is bf16, stride Nc.
template<int AMODE, int GRUH>
__global__ __launch_bounds__(256,2)
void k_mgemm(const void* __restrict__ A_, int sA,
             const u16* __restrict__ W, int sW, size_t tstride,
             const int* __restrict__ T, int nchunks,
             const float* __restrict__ bias, int biasN,
             u16* __restrict__ C, int Nc, int goff)
{
  __shared__ u16 As[128*LK];
  __shared__ u16 Bs[128*LK];
  const int ntile = blockIdx.x, mtile = blockIdx.y, node = blockIdx.z;
  const int tid = threadIdx.x;
  const int t = T[node];
  const int lane = tid & 63, wv = tid >> 6;
  const int wm = wv & 1, wn = wv >> 1;
  const int l16 = lane & 15, quad = lane >> 4;
  const int row0 = mtile*128, col0 = ntile*128;

  f32x4 acc[4][4];
  #pragma unroll
  for (int mt=0; mt<4; ++mt)
  #pragma unroll
  for (int nt=0; nt<4; ++nt){
    const int col = col0 + wn*64 + nt*16 + l16;
    const float bv = bias[node*biasN + col];
    if (GRUH && ntile < 8){
      #pragma unroll
      for (int r=0;r<4;++r){
        const int row = row0 + wm*64 + mt*16 + quad*4 + r;
        acc[mt][nt][r] = bv + b2f(C[(size_t)(node*BB + row)*Nc + col]);
      }
    } else {
      #pragma unroll
      for (int r=0;r<4;++r) acc[mt][nt][r] = bv;
    }
  }

  const int sr = tid >> 1, seg = tid & 1;
  for (int kc = 0; kc < nchunks; ++kc){
    const int k0 = kc*32 + seg*16;
    if (AMODE == 0){
      const u16* srcA = (const u16*)A_ + (size_t)(node*BB + row0 + sr)*sA + k0;
      *(uint4*)&As[sr*LK + seg*16]     = *(const uint4*)srcA;
      *(uint4*)&As[sr*LK + seg*16 + 8] = *(const uint4*)(srcA + 8);
    } else {
      const float* srcA = (const float*)A_ + (size_t)(node*BB + row0 + sr)*sA + k0;
      float4 f0 = *(const float4*)(srcA);
      float4 f1 = *(const float4*)(srcA+4);
      float4 f2 = *(const float4*)(srcA+8);
      float4 f3 = *(const float4*)(srcA+12);
      bf16x8 v0, v1;
      v0[0]=fb(f0.x); v0[1]=fb(f0.y); v0[2]=fb(f0.z); v0[3]=fb(f0.w);
      v0[4]=fb(f1.x); v0[5]=fb(f1.y); v0[6]=fb(f1.z); v0[7]=fb(f1.w);
      v1[0]=fb(f2.x); v1[1]=fb(f2.y); v1[2]=fb(f2.z); v1[3]=fb(f2.w);
      v1[4]=fb(f3.x); v1[5]=fb(f3.y); v1[6]=fb(f3.z); v1[7]=fb(f3.w);
      *(bf16x8*)&As[sr*LK + seg*16]     = v0;
      *(bf16x8*)&As[sr*LK + seg*16 + 8] = v1;
    }
    {
      const u16* srcB = W + (size_t)t*tstride + (size_t)(col0 + sr)*sW + k0;
      *(uint4*)&Bs[sr*LK + seg*16]     = *(const uint4*)srcB;
      *(uint4*)&Bs[sr*LK + seg*16 + 8] = *(const uint4*)(srcB + 8);
    }
    __syncthreads();
    bf16x8 af[4], bfr[4];
    #pragma unroll
    for (int mt=0; mt<4; ++mt) af[mt]  = *(const bf16x8*)&As[(wm*64 + mt*16 + l16)*LK + quad*8];
    #pragma unroll
    for (int nt=0; nt<4; ++nt) bfr[nt] = *(const bf16x8*)&Bs[(wn*64 + nt*16 + l16)*LK + quad*8];
    #pragma unroll
    for (int mt=0; mt<4; ++mt)
    #pragma unroll
    for (int nt=0; nt<4; ++nt)
      acc[mt][nt] = __builtin_amdgcn_mfma_f32_16x16x32_bf16(af[mt], bfr[nt], acc[mt][nt], 0, 0, 0);
    __syncthreads();
  }

  #pragma unroll
  for (int mt=0; mt<4; ++mt)
  #pragma unroll
  for (int nt=0; nt<4; ++nt){
    const int col = col0 + wn*64 + nt*16 + l16;
    const int dcol = GRUH ? ((ntile < 8) ? col : col + 512) : col + goff;
    #pragma unroll
    for (int r=0;r<4;++r){
      const int row = row0 + wm*64 + mt*16 + quad*4 + r;
      C[(size_t)(node*BB + row)*Nc + dcol] = f2b(acc[mt][nt][r]);
    }
  }
}

// ---------------- mixing / GRU / head ----------------

__global__ __launch_bounds__(256)
void k_mix_init(const float* C0, const float* G0s, float* h){
  __shared__ float Gs[441];
  const int tid = threadIdx.x;
  for (int i = tid; i < 441; i += 256) Gs[i] = G0s[i];
  __syncthreads();
  const int b = blockIdx.y;
  const int j = blockIdx.x*256 + tid;
  float P[21];
  #pragma unroll
  for (int m=0;m<21;++m) P[m] = C0[(size_t)(m*BB + b)*HID + j];
  float R[21];
  for (int n=0;n<21;++n){
    float s = 0.f;
    #pragma unroll
    for (int m=0;m<21;++m) s += Gs[n*21+m]*P[m];
    R[n] = s;
  }
  for (int n=0;n<21;++n) h[(size_t)(n*BB + b)*HID + j] = R[n];
}

// Cbig ch: [0:1024)=s1,s2 (xr+hr), [1024:1536)=ic, [1536:2048)=hc2.
// Writes y (bf16) into Cbig ch[0:512)  (safe: P1..P4 preloaded; disjoint per block)
__global__ __launch_bounds__(256)
void k_gru(u16* __restrict__ Cb, const float* __restrict__ Gns, float* __restrict__ h){
  __shared__ float Gs[441];
  const int tid = threadIdx.x;
  for (int i = tid; i < 441; i += 256) Gs[i] = Gns[i];
  __syncthreads();
  const int b = blockIdx.y;
  const int j = blockIdx.x*256 + tid;
  float P1[21], P2[21], P3[21], P4[21];
  #pragma unroll
  for (int m=0;m<21;++m){
    const size_t base = (size_t)(m*BB + b)*NC2 + j;
    P1[m] = b2f(Cb[base]);
    P2[m] = b2f(Cb[base + 512]);
    P3[m] = b2f(Cb[base + 1024]);
    P4[m] = b2f(Cb[base + 1536]);
  }
  for (int n=0;n<21;++n){
    float s1=0.f, s2=0.f, s3=0.f, s4=0.f;
    #pragma unroll
    for (int m=0;m<21;++m){
      const float g = Gs[n*21+m];
      s1 += g*P1[m]; s2 += g*P2[m]; s3 += g*P3[m]; s4 += g*P4[m];
    }
    const size_t hi = (size_t)(n*BB + b)*HID + j;
    const float hc = h[hi];
    const float r  = sigm(s1);
    const float zg = sigm(s2);
    const float nn = ftanh(s3 + r*s4);
    const float hn = (1.f - zg)*nn + zg*hc;
    h[hi] = hn;
    Cb[(size_t)(n*BB + b)*NC2 + j] = f2b(ftanh(hn));   // y
  }
}

// head outputs live in Cbig ch [512:768) bf16
__global__ __launch_bounds__(256)
void k_out(const u16* __restrict__ Cbig, const float* __restrict__ Gqs, const float* __restrict__ Gcs,
           const int* __restrict__ T, const int* __restrict__ flags,
           const void* __restrict__ W3, const void* __restrict__ b3,
           const void* __restrict__ W6, const void* __restrict__ b6,
           float* __restrict__ qc, u16* __restrict__ Axin,
           float* __restrict__ out_dq, float* __restrict__ out_cov, int s)
{
  const int tid = threadIdx.x;
  const int w = blockIdx.x*4 + (tid >> 6);
  const int lane = tid & 63;
  const int b = w / 21, n = w % 21;
  const int t = T[n];
  const int md = flags[0];
  float aq1=0.f, aq2=0.f, ac1=0.f, ac2=0.f;
  #pragma unroll
  for (int m=0;m<21;++m){
    const u16* c = Cbig + (size_t)(m*BB + b)*NC2 + 512;
    const float gq = Gqs[n*21+m], gc = Gcs[n*21+m];
    aq1 += gq*b2f(c[lane]);       aq2 += gq*b2f(c[lane+64]);
    ac1 += gc*b2f(c[lane+128]);   ac2 += gc*b2f(c[lane+192]);
  }
  const float ys1 = ftanh(aq1), ys2 = ftanh(aq2);
  const float yc1 = ftanh(ac1), yc2 = ftanh(ac2);
  float red[9];
  #pragma unroll
  for (int a=0;a<3;++a)
    red[a] = ys1*ldf(W3,(size_t)(t*3+a)*128 + lane,md) + ys2*ldf(W3,(size_t)(t*3+a)*128 + lane + 64,md);
  #pragma unroll
  for (int a=0;a<6;++a)
    red[3+a] = yc1*ldf(W6,(size_t)(t*6+a)*128 + lane,md) + yc2*ldf(W6,(size_t)(t*6+a)*128 + lane + 64,md);
  #pragma unroll
  for (int i=0;i<9;++i){
    red[i] += __shfl_xor(red[i], 32);
    red[i] += __shfl_xor(red[i], 16);
    red[i] += __shfl_xor(red[i], 8);
    red[i] += __shfl_xor(red[i], 4);
    red[i] += __shfl_xor(red[i], 2);
    red[i] += __shfl_xor(red[i], 1);
  }
  const float d0 = red[0] + ldf(b3,(size_t)n*3+0,md);
  const float d1 = red[1] + ldf(b3,(size_t)n*3+1,md);
  const float d2 = red[2] + ldf(b3,(size_t)n*3+2,md);
  const float theta = sqrtf(d0*d0 + d1*d1 + d2*d2);
  const float wq = cosf(0.5f*theta);
  const float kq = (theta > 1e-8f) ? (sinf(0.5f*theta) / fmaxf(theta, 1e-8f)) : 0.5f;
  const float x1 = kq*d0, y1 = kq*d1, z1 = kq*d2;
  if (lane == 0){
    float* q = qc + (size_t)(n*BB + b)*4;
    const float qw=q[0], qx=q[1], qy=q[2], qz=q[3];
    const float nw = wq*qw - (x1*qx + y1*qy + z1*qz);
    const float nx = wq*qx + qw*x1 + (y1*qz - z1*qy);
    const float ny = wq*qy + qw*y1 + (z1*qx - x1*qz);
    const float nz = wq*qz + qw*z1 + (x1*qy - y1*qx);
    q[0]=nw; q[1]=nx; q[2]=ny; q[3]=nz;
    u16* ax = Axin + (size_t)(n*BB + b)*A0S;
    ax[0]=f2b(nw); ax[1]=f2b(nx); ax[2]=f2b(ny); ax[3]=f2b(nz);
    ax[4]=f2b(wq); ax[5]=f2b(x1); ax[6]=f2b(y1); ax[7]=f2b(z1);
    float* od = out_dq + (size_t)((b*PH + s)*NN + n)*4;
    od[0]=wq; od[1]=x1; od[2]=y1; od[3]=z1;
    float* oc = out_cov + (size_t)((b*PH + s)*NN + n)*6;
    for (int a=0;a<6;++a) oc[a] = red[3+a] + ldf(b6,(size_t)n*6+a,md);
  }
}

// ---------------- launch ----------------

extern "C" void kernel_launch(void* const* d_in, const int* in_sizes, int n_in,
                              void* d_out, int out_size, void* d_ws, size_t ws_size,
                              hipStream_t stream)
{
  const void* P[25];
  {
    int j = 0;
    for (int i = 0; i < 25; ++i){
      if (i == 5){ P[i] = nullptr; continue; }
      while (j < n_in && in_sizes[j] == 1) ++j;
      P[i] = (j < n_in) ? d_in[j++] : nullptr;
    }
  }

  char* wsb = (char*)d_ws;
  size_t off = 0;
  auto carve = [&](size_t bytes)->void*{
    void* p = wsb + off;
    off = (off + bytes + 255) & ~(size_t)255;
    return p;
  };

  int*   flags = (int*)  carve(2*4);
  int*   TI    = (int*)  carve(NN*4);
  float* G0s   = (float*)carve(441*4);
  float* Gns   = (float*)carve(441*4);
  float* Gqs   = (float*)carve(441*4);
  float* Gcs   = (float*)carve(441*4);
  float* bihF  = (float*)carve((size_t)NN*G3*4);
  float* bhhF  = (float*)carve((size_t)NN*G3*4);
  float* bqcF  = (float*)carve((size_t)NN*256*4);
  u16*   Axin  = (u16*)  carve((size_t)NN*BB*A0S*2);   // 3.8 MB
  u16*   Wihb  = (u16*)  carve((size_t)4*G3*A0S*2);    // 4.3 MB (padded K)
  u16*   Whhb  = (u16*)  carve((size_t)4*G3*512*2);    // 6.3 MB
  u16*   Wqcb  = (u16*)  carve((size_t)4*256*512*2);   // 1.0 MB
  float* hbuf  = (float*)carve((size_t)NN*BB*HID*4);   // 11.0 MB
  u16*   Cbig  = (u16*)  carve((size_t)NN*BB*NC2*2);   // 22.0 MB
  float* qcv   = (float*)carve((size_t)NN*BB*4*4);
  const size_t NEED = off;   // ~49 MB (< 52 MB proven available)

  float* out_dq  = (float*)d_out;
  float* out_cov = out_dq  + (size_t)BB*PH*NN*4;
  float* out_xt  = out_cov + (size_t)BB*PH*NN*6;

  if (ws_size < NEED){
    float code = 150.0f + (float)(ws_size >> 23);
    k_fill<<<(out_size+255)/256,256,0,stream>>>((float*)d_out, out_size, code);
    return;
  }

  k_detect<<<1,64,0,stream>>>(P[6], P[4], flags);
  k_cvt_i<<<1,64,0,stream>>>(P[4], TI, NN, flags);
  k_prep_G<<<1,128,0,stream>>>(P[8],P[13],P[14],P[17],P[20],flags, G0s,Gns,Gqs,Gcs);
  k_cvt_f<<<(NN*G3+255)/256,256,0,stream>>>(P[11], bihF, NN*G3, flags);
  k_cvt_f<<<(NN*G3+255)/256,256,0,stream>>>(P[12], bhhF, NN*G3, flags);
  k_bqc<<<(NN*256+255)/256,256,0,stream>>>(P[16],P[19],bqcF,flags);
  k_build_A0<<<(NN*BB*A0S+255)/256,256,0,stream>>>(P[0],P[2],P[1],flags,Axin);
  k_cvt_wpad<<<(4*G3*A0S+255)/256,256,0,stream>>>(P[9], Wihb, flags);
  k_cvt_w<<<(4*G3*512+255)/256,256,0,stream>>>(P[10], Whhb, 4*G3*512, flags);
  k_cvt_wqc<<<(4*256*512+255)/256,256,0,stream>>>(P[15],P[18],Wqcb,flags);

  // rnn_h pre-mix (one-shot, naive): hbuf = Axin(x_{t-1}) . W0^T + b0
  k_ngemm<1><<<dim3(HID/8,NN),256,0,stream>>>(Axin,A0S, P[6],328,(size_t)512*328,
      P[7],512, TI,flags, 328, hbuf,512);
  k_mix_init<<<dim3(2,BB),256,0,stream>>>(hbuf,G0s,hbuf);
  k_init_state<<<NN,256,0,stream>>>(P[0],P[3],flags,Axin,qcv,out_xt);

  for (int s=0; s<PH; ++s){
    // xr: Cbig[0:1536) = Axin . Wih^T + bih     (MFMA, K=328 zero-padded to 352)
    k_mgemm<0,0><<<dim3(12,2,NN),256,0,stream>>>(Axin,A0S, Wihb,A0S,(size_t)G3*A0S,
        TI, 11, bihF,G3, Cbig,NC2, 0);
    // hr: Cbig[0:1024) += h.Whh^T+bhh ; Cbig[1536:2048) = h.Whh^T[1024:)+bhh
    k_mgemm<1,1><<<dim3(12,2,NN),256,0,stream>>>(hbuf,HID, Whhb,512,(size_t)G3*512,
        TI, 16, bhhF,G3, Cbig,NC2, 0);
    // GRU: h update; y -> Cbig ch[0:512)
    k_gru<<<dim3(2,BB),256,0,stream>>>(Cbig,Gns,hbuf);
    // head: Cbig[512:768) = y.[Wq|Wc]^T + [bq|bc]
    k_mgemm<0,0><<<dim3(2,2,NN),256,0,stream>>>(Cbig,NC2, Wqcb,512,(size_t)256*512,
        TI, 16, bqcF,256, Cbig,NC2, 512);
    k_out<<<(NN*BB)/4,256,0,stream>>>(Cbig,Gqs,Gcs,TI,flags,P[21],P[22],P[23],P[24],
        qcv,Axin,out_dq,out_cov,s);
  }
}

// Round 12
// 1317.902 us; speedup vs baseline: 5.8424x; 1.0163x over previous
//
#include <hip/hip_runtime.h>

typedef unsigned short u16;
typedef __bf16 bf16_t;
typedef bf16_t bf16x8 __attribute__((ext_vector_type(8)));
typedef float f32x4 __attribute__((ext_vector_type(4)));
typedef long long i64;

#define NN   21
#define BB   256
#define HID  512
#define G3   1536
#define NC2  2048
#define A0S  352
#define PH   12
#define WSK  516
#define LK   40    // LDS row stride (32+8 pad) bf16 elems
#define KP   544   // packed gate K (512 h + 8 x + 24 pad)

__device__ __forceinline__ u16 f2b(float f){ bf16_t b = (bf16_t)f; return __builtin_bit_cast(u16, b); }
__device__ __forceinline__ float b2f(u16 u){ bf16_t b = __builtin_bit_cast(bf16_t, u); return (float)b; }
__device__ __forceinline__ bf16_t fb(float f){ return (bf16_t)f; }
__device__ __forceinline__ float sigm(float x){ return 1.0f / (1.0f + __expf(-x)); }
__device__ __forceinline__ float ftanh(float x){
  x = fminf(15.0f, fmaxf(-15.0f, x));
  float e = __expf(2.0f * x);
  return (e - 1.0f) / (e + 1.0f);
}
__device__ __forceinline__ float ldf(const void* p, size_t idx, int mode){
  if (mode == 2) return b2f(((const u16*)p)[idx]);
  if (mode == 1) return (float)((const double*)p)[idx];
  return ((const float*)p)[idx];
}

__global__ void k_fill(float* out, int n, float c){
  int idx = blockIdx.x*256 + threadIdx.x;
  if (idx < n) out[idx] = c;
}

__global__ void k_detect(const void* w0raw, const void* traw, int* flags){
  if (threadIdx.x != 0 || blockIdx.x != 0) return;
  const float*  v32 = (const float*)w0raw;
  const double* v64 = (const double*)w0raw;
  const u16*    vbf = (const u16*)w0raw;
  int c32 = 0, c64 = 0, cbf = 0;
  for (int i = 0; i < 64; ++i){
    float a32 = fabsf(v32[i]);
    if (a32 >= 1e-8f && a32 <= 1e4f) ++c32;
    double a64 = fabs(v64[i]);
    if (a64 >= 1e-8 && a64 <= 1e4) ++c64;
    float abf = fabsf(b2f(vbf[i]));
    if (abf >= 1e-8f && abf <= 1e4f) ++cbf;
  }
  int mode;
  if (cbf >= 60 && c32 < 48) mode = 2;
  else if (c32 >= 48)        mode = 0;
  else if (c64 >= 48)        mode = 1;
  else                       mode = 2;
  flags[0] = mode;
  const int* tw = (const int*)traw;
  int ok64 = 1;
  for (int i = 0; i < NN; ++i){
    unsigned lo = (unsigned)tw[2*i];
    int hi = tw[2*i+1];
    if (hi != 0 || lo >= 4u) { ok64 = 0; break; }
  }
  flags[1] = ok64;
}
__global__ void k_cvt_i(const void* src, int* dst, int n, const int* flags){
  int idx = threadIdx.x;
  if (idx >= n) return;
  if (flags[1]) dst[idx] = (int)((const i64*)src)[idx];
  else          dst[idx] = ((const int*)src)[idx];
}
__global__ void k_cvt_f(const void* src, float* dst, int n, const int* flags){
  int idx = blockIdx.x*256 + threadIdx.x;
  if (idx < n) dst[idx] = ldf(src, idx, flags[0]);
}
// generic: W raw (srcK per row) -> bf16 padded to dstK
__global__ void k_cvt_wpadg(const void* W, u16* dst, int rows, int srcK, int dstK, const int* flags){
  int idx = blockIdx.x*256 + threadIdx.x;
  if (idx >= rows*dstK) return;
  int k = idx % dstK, r = idx / dstK;
  dst[idx] = (k < srcK) ? f2b(ldf(W, (size_t)r*srcK + k, flags[0])) : (u16)0;
}
__global__ void k_cvt_w(const void* W, u16* dst, int n, const int* flags){
  int idx = blockIdx.x*256 + threadIdx.x;
  if (idx < n) dst[idx] = f2b(ldf(W, idx, flags[0]));
}
// Wstat[t][g][k2] = Wih[t][g][8+k2], k2 in [0,320)
__global__ void k_cvt_wstat(const void* Wih, u16* dst, const int* flags){
  int idx = blockIdx.x*256 + threadIdx.x;
  if (idx >= 4*G3*320) return;
  int k2 = idx % 320, tg = idx / 320;
  dst[idx] = f2b(ldf(Wih, (size_t)tg*328 + 8 + k2, flags[0]));
}
// Wpack[t][g'][k] (2048 x 544) — R0 layout, audited:
//  g'<1024: [Whh[g'][0:512] | Wih[g'][0:8] | 0]
//  1024<=g'<1536: [0(512) | Wih[g'][0:8] | 0]
//  1536<=g'<2048: [Whh[g'-512][0:512] | 0]
__global__ void k_pack_wpack(const void* Whh, const void* Wih, u16* Wp, const int* flags){
  int idx = blockIdx.x*256 + threadIdx.x;
  if (idx >= 4*NC2*KP) return;
  const int md = flags[0];
  int k  = idx % KP;
  int tg = idx / KP;
  int g  = tg % NC2;
  int t  = tg / NC2;
  float v = 0.f;
  if (g < 1024){
    if (k < 512)             v = ldf(Whh, ((size_t)(t*G3 + g) << 9) + k, md);
    else if (k < 520)        v = ldf(Wih, (size_t)(t*G3 + g)*328 + (k - 512), md);
  } else if (g < 1536){
    if (k >= 512 && k < 520) v = ldf(Wih, (size_t)(t*G3 + g)*328 + (k - 512), md);
  } else {
    if (k < 512)             v = ldf(Whh, ((size_t)(t*G3 + (g - 512)) << 9) + k, md);
  }
  Wp[idx] = f2b(v);
}
// Wqc[t][g][k] bf16: g<128 -> Wq, else Wc
__global__ void k_cvt_wqc(const void* Wq, const void* Wc, u16* dst, const int* flags){
  int idx = blockIdx.x*256 + threadIdx.x;
  if (idx >= 4*256*512) return;
  int k  = idx & 511;
  int tg = idx >> 9;
  int g  = tg & 255;
  int t  = tg >> 8;
  const int md = flags[0];
  dst[idx] = f2b((g < 128) ? ldf(Wq, ((size_t)(t*128 + g) << 9) + k, md)
                           : ldf(Wc, ((size_t)(t*128 + (g-128)) << 9) + k, md));
}
__global__ void k_bqc(const void* bq, const void* bc, float* bqc, const int* flags){
  int idx = blockIdx.x*256 + threadIdx.x;
  if (idx >= NN*256) return;
  int o = idx & 255; int n = idx >> 8;
  const int md = flags[0];
  bqc[idx] = (o < 128) ? ldf(bq,(size_t)n*128+o,md) : ldf(bc,(size_t)n*128+(o-128),md);
}
// biasS[n][g], g<1536: bih (+bhh for g<1024). bhh2[n][j] = bhh[n][1024+j].
__global__ void k_biasS(const void* bih, const void* bhh, float* biasS, float* bhh2, const int* flags){
  int idx = blockIdx.x*256 + threadIdx.x;
  if (idx >= NN*G3) return;
  const int md = flags[0];
  int g = idx % G3;
  float v = ldf(bih, idx, md);
  if (g < 1024) v += ldf(bhh, idx, md);
  biasS[idx] = v;
  if (g >= 1024){
    int n = idx / G3;
    bhh2[n*512 + (g - 1024)] = ldf(bhh, idx, md);
  }
}

__global__ void k_prep_G(const void* G0, const void* Grnn, const void* GA,
                         const void* Gq, const void* Gc, const int* flags,
                         float* G0s, float* Gns, float* Gqs, float* Gcs){
  int tid = threadIdx.x;
  if (tid >= 84) return;
  const int md = flags[0];
  int mat = tid / 21, row = tid % 21;
  const void* src = mat==0 ? G0 : mat==1 ? Grnn : mat==2 ? Gq : Gc;
  float* dst      = mat==0 ? G0s : mat==1 ? Gns : mat==2 ? Gqs : Gcs;
  float s = 0.f;
  for (int m=0;m<21;++m) s += fabsf(ldf(src,row*21+m,md));
  s = fmaxf(s, 1e-12f);
  for (int m=0;m<21;++m){
    float v = ldf(src,row*21+m,md) / s;
    if (mat==1) v += ldf(GA,row*21+m,md);
    dst[row*21+m] = v;
  }
}

__global__ void k_build_A0(const void* x, const void* z, const void* hin,
                           const int* flags, u16* A0){
  int idx = blockIdx.x*256 + threadIdx.x;
  if (idx >= NN*BB*A0S) return;
  const int md = flags[0];
  int k  = idx % A0S;
  int nb = idx / A0S;
  int b  = nb % BB;
  int n  = nb / BB;
  float v = 0.f;
  if (k < 8)        v = ldf(x, ((size_t)(b*2 + 0)*NN + n)*8 + k, md);
  else if (k < 72)  v = ldf(z, ((size_t)b*NN + n)*64 + (k - 8), md);
  else if (k < 328) v = ldf(hin, ((size_t)b*NN + n)*256 + (k - 72), md);
  A0[idx] = f2b(v);
}

__global__ void k_init_state(const void* x, const void* qt, const int* flags,
                             u16* Axin, float* qc, float* out2){
  int b = threadIdx.x; int n = blockIdx.x;
  const int md = flags[0];
  for (int f=0; f<8; ++f){
    float raw = ldf(x, ((size_t)(b*2 + 1)*NN + n)*8 + f, md);
    Axin[(size_t)(n*BB + b)*A0S + f] = f2b(raw);
    out2[(b*NN + n)*8 + f] = raw;
  }
  for (int c=0; c<4; ++c) qc[(n*BB + b)*4 + c] = ldf(qt, ((size_t)b*NN + n)*4 + c, md);
}

// ---------------- naive GEMM (Path B W0 init) ----------------
template<int ABF>
__global__ __launch_bounds__(256)
void k_ngemm(const void* __restrict__ A_, int sA,
             const void* __restrict__ W_, int sW, size_t tstride,
             const void* __restrict__ bias_, int biasN,
             const int* __restrict__ T, const int* __restrict__ flags, int K,
             float* __restrict__ C, int Nc)
{
  __shared__ float Ws[8*WSK];
  const int node = blockIdx.y;
  const int g0   = blockIdx.x*8;
  const int tid  = threadIdx.x;
  const int t    = T[node];
  const int md   = flags[0];
  for (int idx = tid; idx < 8*K; idx += 256){
    int gg = idx / K, kk = idx - gg*K;
    Ws[gg*WSK + kk] = ldf(W_, (size_t)t*tstride + (size_t)(g0+gg)*sW + kk, md);
  }
  __syncthreads();
  const int b = tid;
  const float* Af = (const float*)A_;
  const u16*   Ab = (const u16*)A_;
  float acc[8];
  #pragma unroll
  for (int gg=0; gg<8; ++gg) acc[gg] = ldf(bias_, (size_t)node*biasN + g0 + gg, md);
  const size_t abase = (size_t)(node*BB + b)*sA;
  for (int k=0; k<K; ++k){
    const float av = ABF ? b2f(Ab[abase + k]) : Af[abase + k];
    #pragma unroll
    for (int gg=0; gg<8; ++gg) acc[gg] += av * Ws[gg*WSK + k];
  }
  #pragma unroll
  for (int gg=0; gg<8; ++gg)
    C[(size_t)(node*BB + b)*Nc + g0 + gg] = acc[gg];
}

// ---------------- MFMA GEMM (generic) ----------------
// AMODE 0: A bf16 stride sA. AMODE 1: A fp32 stride sA.
// GRUH (Path B): ntile<8 accumulate onto C at col; else fresh at col+512.
// FOUT: 1 -> C is float*, write fp32.
template<int AMODE, int GRUH, int FOUT>
__global__ __launch_bounds__(256,2)
void k_mgemm(const void* __restrict__ A_, int sA,
             const u16* __restrict__ W, int sW, size_t tstride,
             const int* __restrict__ T, int nchunks,
             const float* __restrict__ bias, int biasN,
             void* __restrict__ C_, int Nc, int goff)
{
  __shared__ u16 As[128*LK];
  __shared__ u16 Bs[128*LK];
  const int ntile = blockIdx.x, mtile = blockIdx.y, node = blockIdx.z;
  const int tid = threadIdx.x;
  const int t = T[node];
  const int lane = tid & 63, wv = tid >> 6;
  const int wm = wv & 1, wn = wv >> 1;
  const int l16 = lane & 15, quad = lane >> 4;
  const int row0 = mtile*128, col0 = ntile*128;
  u16* Cb = (u16*)C_;
  float* Cf = (float*)C_;

  f32x4 acc[4][4];
  #pragma unroll
  for (int mt=0; mt<4; ++mt)
  #pragma unroll
  for (int nt=0; nt<4; ++nt){
    const int col = col0 + wn*64 + nt*16 + l16;
    const float bv = bias[node*biasN + col];
    if (GRUH && ntile < 8){
      #pragma unroll
      for (int r=0;r<4;++r){
        const int row = row0 + wm*64 + mt*16 + quad*4 + r;
        acc[mt][nt][r] = bv + b2f(Cb[(size_t)(node*BB + row)*Nc + col]);
      }
    } else {
      #pragma unroll
      for (int r=0;r<4;++r) acc[mt][nt][r] = bv;
    }
  }

  const int sr = tid >> 1, seg = tid & 1;
  for (int kc = 0; kc < nchunks; ++kc){
    const int k0 = kc*32 + seg*16;
    if (AMODE == 0){
      const u16* srcA = (const u16*)A_ + (size_t)(node*BB + row0 + sr)*sA + k0;
      *(uint4*)&As[sr*LK + seg*16]     = *(const uint4*)srcA;
      *(uint4*)&As[sr*LK + seg*16 + 8] = *(const uint4*)(srcA + 8);
    } else {
      const float* srcA = (const float*)A_ + (size_t)(node*BB + row0 + sr)*sA + k0;
      float4 f0 = *(const float4*)(srcA);
      float4 f1 = *(const float4*)(srcA+4);
      float4 f2 = *(const float4*)(srcA+8);
      float4 f3 = *(const float4*)(srcA+12);
      bf16x8 v0, v1;
      v0[0]=fb(f0.x); v0[1]=fb(f0.y); v0[2]=fb(f0.z); v0[3]=fb(f0.w);
      v0[4]=fb(f1.x); v0[5]=fb(f1.y); v0[6]=fb(f1.z); v0[7]=fb(f1.w);
      v1[0]=fb(f2.x); v1[1]=fb(f2.y); v1[2]=fb(f2.z); v1[3]=fb(f2.w);
      v1[4]=fb(f3.x); v1[5]=fb(f3.y); v1[6]=fb(f3.z); v1[7]=fb(f3.w);
      *(bf16x8*)&As[sr*LK + seg*16]     = v0;
      *(bf16x8*)&As[sr*LK + seg*16 + 8] = v1;
    }
    {
      const u16* srcB = W + (size_t)t*tstride + (size_t)(col0 + sr)*sW + k0;
      *(uint4*)&Bs[sr*LK + seg*16]     = *(const uint4*)srcB;
      *(uint4*)&Bs[sr*LK + seg*16 + 8] = *(const uint4*)(srcB + 8);
    }
    __syncthreads();
    bf16x8 af[4], bfr[4];
    #pragma unroll
    for (int mt=0; mt<4; ++mt) af[mt]  = *(const bf16x8*)&As[(wm*64 + mt*16 + l16)*LK + quad*8];
    #pragma unroll
    for (int nt=0; nt<4; ++nt) bfr[nt] = *(const bf16x8*)&Bs[(wn*64 + nt*16 + l16)*LK + quad*8];
    #pragma unroll
    for (int mt=0; mt<4; ++mt)
    #pragma unroll
    for (int nt=0; nt<4; ++nt)
      acc[mt][nt] = __builtin_amdgcn_mfma_f32_16x16x32_bf16(af[mt], bfr[nt], acc[mt][nt], 0, 0, 0);
    __syncthreads();
  }

  #pragma unroll
  for (int mt=0; mt<4; ++mt)
  #pragma unroll
  for (int nt=0; nt<4; ++nt){
    const int col = col0 + wn*64 + nt*16 + l16;
    const int dcol = GRUH ? ((ntile < 8) ? col : col + 512) : col + goff;
    #pragma unroll
    for (int r=0;r<4;++r){
      const int row = row0 + wm*64 + mt*16 + quad*4 + r;
      if (FOUT) Cf[(size_t)(node*BB + row)*Nc + dcol] = acc[mt][nt][r];
      else      Cb[(size_t)(node*BB + row)*Nc + dcol] = f2b(acc[mt][nt][r]);
    }
  }
}

// ---------------- fused gate GEMM (Path A) ----------------
// Cbig[n][b][g'] = init + sum_k Apack[k]*Wpack[T[n]][g'][k]
//  Apack: k<512 = hbuf fp32; k in [512,520) = Axin x_c bf16; else 0
//  init: g'<1536 -> Sbuf bf16 per-row; g'>=1536 -> bhh2[n][g'-1536]
//  chunk ranges: ntile<8: all 17; 8..11 (ic): only 16; 12..15 (hc2): 0..15
__global__ __launch_bounds__(256,2)
void k_fgemm(const float* __restrict__ H, const u16* __restrict__ Ax,
             const u16* __restrict__ Wp,
             const int* __restrict__ T,
             const u16* __restrict__ Sbuf, const float* __restrict__ bhh2,
             u16* __restrict__ C)
{
  __shared__ u16 As[128*LK];
  __shared__ u16 Bs[128*LK];
  const int ntile = blockIdx.x, mtile = blockIdx.y, node = blockIdx.z;
  const int tid = threadIdx.x;
  const int t = T[node];
  const int lane = tid & 63, wv = tid >> 6;
  const int wm = wv & 1, wn = wv >> 1;
  const int l16 = lane & 15, quad = lane >> 4;
  const int row0 = mtile*128, col0 = ntile*128;

  f32x4 acc[4][4];
  #pragma unroll
  for (int mt=0; mt<4; ++mt)
  #pragma unroll
  for (int nt=0; nt<4; ++nt){
    const int col = col0 + wn*64 + nt*16 + l16;
    #pragma unroll
    for (int r=0;r<4;++r){
      const int row = row0 + wm*64 + mt*16 + quad*4 + r;
      acc[mt][nt][r] = (col < 1536)
        ? b2f(Sbuf[(size_t)(node*BB + row)*G3 + col])
        : bhh2[node*512 + (col - 1536)];
    }
  }

  int kc0 = 0, kc1 = 17;
  if (ntile >= 8 && ntile < 12) kc0 = 16;       // ic: only x chunk
  else if (ntile >= 12)         kc1 = 16;       // hc2: no x chunk

  const int sr = tid >> 1, seg = tid & 1;
  for (int kc = kc0; kc < kc1; ++kc){
    const int k0 = kc*32 + seg*16;
    if (kc < 16){
      const float* srcA = H + (size_t)(node*BB + row0 + sr)*HID + k0;
      float4 f0 = *(const float4*)(srcA);
      float4 f1 = *(const float4*)(srcA+4);
      float4 f2 = *(const float4*)(srcA+8);
      float4 f3 = *(const float4*)(srcA+12);
      bf16x8 v0, v1;
      v0[0]=fb(f0.x); v0[1]=fb(f0.y); v0[2]=fb(f0.z); v0[3]=fb(f0.w);
      v0[4]=fb(f1.x); v0[5]=fb(f1.y); v0[6]=fb(f1.z); v0[7]=fb(f1.w);
      v1[0]=fb(f2.x); v1[1]=fb(f2.y); v1[2]=fb(f2.z); v1[3]=fb(f2.w);
      v1[4]=fb(f3.x); v1[5]=fb(f3.y); v1[6]=fb(f3.z); v1[7]=fb(f3.w);
      *(bf16x8*)&As[sr*LK + seg*16]     = v0;
      *(bf16x8*)&As[sr*LK + seg*16 + 8] = v1;
    } else {
      uint4 zz; zz.x = zz.y = zz.z = zz.w = 0u;
      uint4 u0 = zz;
      if (seg == 0) u0 = *(const uint4*)(Ax + (size_t)(node*BB + row0 + sr)*A0S);  // 8 x_c bf16
      *(uint4*)&As[sr*LK + seg*16]     = u0;
      *(uint4*)&As[sr*LK + seg*16 + 8] = zz;
    }
    {
      const u16* srcB = Wp + (size_t)t*NC2*KP + (size_t)(col0 + sr)*KP + k0;
      *(uint4*)&Bs[sr*LK + seg*16]     = *(const uint4*)srcB;
      *(uint4*)&Bs[sr*LK + seg*16 + 8] = *(const uint4*)(srcB + 8);
    }
    __syncthreads();
    bf16x8 af[4], bfr[4];
    #pragma unroll
    for (int mt=0; mt<4; ++mt) af[mt]  = *(const bf16x8*)&As[(wm*64 + mt*16 + l16)*LK + quad*8];
    #pragma unroll
    for (int nt=0; nt<4; ++nt) bfr[nt] = *(const bf16x8*)&Bs[(wn*64 + nt*16 + l16)*LK + quad*8];
    #pragma unroll
    for (int mt=0; mt<4; ++mt)
    #pragma unroll
    for (int nt=0; nt<4; ++nt)
      acc[mt][nt] = __builtin_amdgcn_mfma_f32_16x16x32_bf16(af[mt], bfr[nt], acc[mt][nt], 0, 0, 0);
    __syncthreads();
  }

  #pragma unroll
  for (int mt=0; mt<4; ++mt)
  #pragma unroll
  for (int nt=0; nt<4; ++nt){
    const int col = col0 + wn*64 + nt*16 + l16;
    #pragma unroll
    for (int r=0;r<4;++r){
      const int row = row0 + wm*64 + mt*16 + quad*4 + r;
      C[(size_t)(node*BB + row)*NC2 + col] = f2b(acc[mt][nt][r]);
    }
  }
}

// ---------------- mixing / GRU / head ----------------

__global__ __launch_bounds__(256)
void k_mix_init(const float* C0, const float* G0s, float* h){
  __shared__ float Gs[441];
  const int tid = threadIdx.x;
  for (int i = tid; i < 441; i += 256) Gs[i] = G0s[i];
  __syncthreads();
  const int b = blockIdx.y;
  const int j = blockIdx.x*256 + tid;
  float P[21];
  #pragma unroll
  for (int m=0;m<21;++m) P[m] = C0[(size_t)(m*BB + b)*HID + j];
  float R[21];
  for (int n=0;n<21;++n){
    float s = 0.f;
    #pragma unroll
    for (int m=0;m<21;++m) s += Gs[n*21+m]*P[m];
    R[n] = s;
  }
  for (int n=0;n<21;++n) h[(size_t)(n*BB + b)*HID + j] = R[n];
}

// Cbig ch: [0:1024)=s1,s2, [1024:1536)=ic, [1536:2048)=hc2. Writes y into ch[0:512).
__global__ __launch_bounds__(256)
void k_gru(u16* __restrict__ Cb, const float* __restrict__ Gns, float* __restrict__ h){
  __shared__ float Gs[441];
  const int tid = threadIdx.x;
  for (int i = tid; i < 441; i += 256) Gs[i] = Gns[i];
  __syncthreads();
  const int b = blockIdx.y;
  const int j = blockIdx.x*256 + tid;
  float P1[21], P2[21], P3[21], P4[21];
  #pragma unroll
  for (int m=0;m<21;++m){
    const size_t base = (size_t)(m*BB + b)*NC2 + j;
    P1[m] = b2f(Cb[base]);
    P2[m] = b2f(Cb[base + 512]);
    P3[m] = b2f(Cb[base + 1024]);
    P4[m] = b2f(Cb[base + 1536]);
  }
  for (int n=0;n<21;++n){
    float s1=0.f, s2=0.f, s3=0.f, s4=0.f;
    #pragma unroll
    for (int m=0;m<21;++m){
      const float g = Gs[n*21+m];
      s1 += g*P1[m]; s2 += g*P2[m]; s3 += g*P3[m]; s4 += g*P4[m];
    }
    const size_t hi = (size_t)(n*BB + b)*HID + j;
    const float hc = h[hi];
    const float r  = sigm(s1);
    const float zg = sigm(s2);
    const float nn = ftanh(s3 + r*s4);
    const float hn = (1.f - zg)*nn + zg*hc;
    h[hi] = hn;
    Cb[(size_t)(n*BB + b)*NC2 + j] = f2b(ftanh(hn));   // y
  }
}

__global__ __launch_bounds__(256)
void k_out(const u16* __restrict__ Cbig, const float* __restrict__ Gqs, const float* __restrict__ Gcs,
           const int* __restrict__ T, const int* __restrict__ flags,
           const void* __restrict__ W3, const void* __restrict__ b3,
           const void* __restrict__ W6, const void* __restrict__ b6,
           float* __restrict__ qc, u16* __restrict__ Axin,
           float* __restrict__ out_dq, float* __restrict__ out_cov, int s)
{
  const int tid = threadIdx.x;
  const int w = blockIdx.x*4 + (tid >> 6);
  const int lane = tid & 63;
  const int b = w / 21, n = w % 21;
  const int t = T[n];
  const int md = flags[0];
  float aq1=0.f, aq2=0.f, ac1=0.f, ac2=0.f;
  #pragma unroll
  for (int m=0;m<21;++m){
    const u16* c = Cbig + (size_t)(m*BB + b)*NC2 + 512;
    const float gq = Gqs[n*21+m], gc = Gcs[n*21+m];
    aq1 += gq*b2f(c[lane]);       aq2 += gq*b2f(c[lane+64]);
    ac1 += gc*b2f(c[lane+128]);   ac2 += gc*b2f(c[lane+192]);
  }
  const float ys1 = ftanh(aq1), ys2 = ftanh(aq2);
  const float yc1 = ftanh(ac1), yc2 = ftanh(ac2);
  float red[9];
  #pragma unroll
  for (int a=0;a<3;++a)
    red[a] = ys1*ldf(W3,(size_t)(t*3+a)*128 + lane,md) + ys2*ldf(W3,(size_t)(t*3+a)*128 + lane + 64,md);
  #pragma unroll
  for (int a=0;a<6;++a)
    red[3+a] = yc1*ldf(W6,(size_t)(t*6+a)*128 + lane,md) + yc2*ldf(W6,(size_t)(t*6+a)*128 + lane + 64,md);
  #pragma unroll
  for (int i=0;i<9;++i){
    red[i] += __shfl_xor(red[i], 32);
    red[i] += __shfl_xor(red[i], 16);
    red[i] += __shfl_xor(red[i], 8);
    red[i] += __shfl_xor(red[i], 4);
    red[i] += __shfl_xor(red[i], 2);
    red[i] += __shfl_xor(red[i], 1);
  }
  const float d0 = red[0] + ldf(b3,(size_t)n*3+0,md);
  const float d1 = red[1] + ldf(b3,(size_t)n*3+1,md);
  const float d2 = red[2] + ldf(b3,(size_t)n*3+2,md);
  const float theta = sqrtf(d0*d0 + d1*d1 + d2*d2);
  const float wq = cosf(0.5f*theta);
  const float kq = (theta > 1e-8f) ? (sinf(0.5f*theta) / fmaxf(theta, 1e-8f)) : 0.5f;
  const float x1 = kq*d0, y1 = kq*d1, z1 = kq*d2;
  if (lane == 0){
    float* q = qc + (size_t)(n*BB + b)*4;
    const float qw=q[0], qx=q[1], qy=q[2], qz=q[3];
    const float nw = wq*qw - (x1*qx + y1*qy + z1*qz);
    const float nx = wq*qx + qw*x1 + (y1*qz - z1*qy);
    const float ny = wq*qy + qw*y1 + (z1*qx - x1*qz);
    const float nz = wq*qz + qw*z1 + (x1*qy - y1*qx);
    q[0]=nw; q[1]=nx; q[2]=ny; q[3]=nz;
    u16* ax = Axin + (size_t)(n*BB + b)*A0S;
    ax[0]=f2b(nw); ax[1]=f2b(nx); ax[2]=f2b(ny); ax[3]=f2b(nz);
    ax[4]=f2b(wq); ax[5]=f2b(x1); ax[6]=f2b(y1); ax[7]=f2b(z1);
    float* od = out_dq + (size_t)((b*PH + s)*NN + n)*4;
    od[0]=wq; od[1]=x1; od[2]=y1; od[3]=z1;
    float* oc = out_cov + (size_t)((b*PH + s)*NN + n)*6;
    for (int a=0;a<6;++a) oc[a] = red[3+a] + ldf(b6,(size_t)n*6+a,md);
  }
}

// ---------------- launch ----------------

extern "C" void kernel_launch(void* const* d_in, const int* in_sizes, int n_in,
                              void* d_out, int out_size, void* d_ws, size_t ws_size,
                              hipStream_t stream)
{
  const void* P[25];
  {
    int j = 0;
    for (int i = 0; i < 25; ++i){
      if (i == 5){ P[i] = nullptr; continue; }
      while (j < n_in && in_sizes[j] == 1) ++j;
      P[i] = (j < n_in) ? d_in[j++] : nullptr;
    }
  }

  float* out_dq  = (float*)d_out;
  float* out_cov = out_dq  + (size_t)BB*PH*NN*4;
  float* out_xt  = out_cov + (size_t)BB*PH*NN*6;

  char* wsb = (char*)d_ws;
  size_t off = 0;
  auto carve = [&](size_t bytes)->void*{
    void* p = wsb + off;
    off = (off + bytes + 255) & ~(size_t)255;
    return p;
  };

  // common small buffers
  int*   flags = (int*)  carve(2*4);
  int*   TI    = (int*)  carve(NN*4);
  float* G0s   = (float*)carve(441*4);
  float* Gns   = (float*)carve(441*4);
  float* Gqs   = (float*)carve(441*4);
  float* Gcs   = (float*)carve(441*4);
  float* bqcF  = (float*)carve((size_t)NN*256*4);
  float* qcv   = (float*)carve((size_t)NN*BB*4*4);
  u16*   Axin  = (u16*)  carve((size_t)NN*BB*A0S*2);
  u16*   Wqcb  = (u16*)  carve((size_t)4*256*512*2);
  float* hbuf  = (float*)carve((size_t)NN*BB*HID*4);
  u16*   Cbig  = (u16*)  carve((size_t)NN*BB*NC2*2);
  const size_t COMMON = off;

  // Path A extras
  size_t offA = off;
  auto carveA = [&](size_t bytes)->void*{
    void* p = wsb + offA;
    offA = (offA + bytes + 255) & ~(size_t)255;
    return p;
  };
  float* b0F   = (float*)carveA((size_t)NN*HID*4);
  float* biasS = (float*)carveA((size_t)NN*G3*4);
  float* bhh2F = (float*)carveA((size_t)NN*512*4);
  u16*   W0b   = (u16*)  carveA((size_t)4*HID*A0S*2);
  u16*   Wstat = (u16*)  carveA((size_t)4*G3*320*2);
  u16*   Wpack = (u16*)  carveA((size_t)4*NC2*KP*2);
  u16*   Sbuf  = (u16*)  carveA((size_t)NN*BB*G3*2);
  const size_t NEED_A = offA;

  // Path B extras (R11 layout)
  size_t offB = off;
  auto carveB = [&](size_t bytes)->void*{
    void* p = wsb + offB;
    offB = (offB + bytes + 255) & ~(size_t)255;
    return p;
  };
  float* bihF  = (float*)carveB((size_t)NN*G3*4);
  float* bhhF  = (float*)carveB((size_t)NN*G3*4);
  u16*   Wihb  = (u16*)  carveB((size_t)4*G3*A0S*2);
  u16*   Whhb  = (u16*)  carveB((size_t)4*G3*512*2);
  const size_t NEED_B = offB;

  if (ws_size < NEED_B){
    float code = 150.0f + (float)(ws_size >> 23);
    k_fill<<<(out_size+255)/256,256,0,stream>>>((float*)d_out, out_size, code);
    return;
  }
  (void)COMMON;

  // common prep
  k_detect<<<1,64,0,stream>>>(P[6], P[4], flags);
  k_cvt_i<<<1,64,0,stream>>>(P[4], TI, NN, flags);
  k_prep_G<<<1,128,0,stream>>>(P[8],P[13],P[14],P[17],P[20],flags, G0s,Gns,Gqs,Gcs);
  k_bqc<<<(NN*256+255)/256,256,0,stream>>>(P[16],P[19],bqcF,flags);
  k_build_A0<<<(NN*BB*A0S+255)/256,256,0,stream>>>(P[0],P[2],P[1],flags,Axin);
  k_cvt_wqc<<<(4*256*512+255)/256,256,0,stream>>>(P[15],P[18],Wqcb,flags);

  if (ws_size >= NEED_A){
    // ---- Path A: fused static-precompute pipeline ----
    k_cvt_f<<<(NN*HID+255)/256,256,0,stream>>>(P[7], b0F, NN*HID, flags);
    k_biasS<<<(NN*G3+255)/256,256,0,stream>>>(P[11],P[12],biasS,bhh2F,flags);
    k_cvt_wpadg<<<(4*HID*A0S+255)/256,256,0,stream>>>(P[6], W0b, 4*HID, 328, A0S, flags);
    k_cvt_wstat<<<(4*G3*320+255)/256,256,0,stream>>>(P[9], Wstat, flags);
    k_pack_wpack<<<(4*NC2*KP+255)/256,256,0,stream>>>(P[10], P[9], Wpack, flags);

    // rnn_h pre-mix via MFMA: hbuf = Axin(x_{t-1}) . W0^T + b0
    k_mgemm<0,0,1><<<dim3(4,2,NN),256,0,stream>>>(Axin,A0S, W0b,A0S,(size_t)HID*A0S,
        TI, 11, b0F,HID, hbuf,HID, 0);
    k_mix_init<<<dim3(2,BB),256,0,stream>>>(hbuf,G0s,hbuf);
    // Sbuf = h_z . Wih[:,8:]^T + biasS   (channels 0..1535)
    k_mgemm<0,0,0><<<dim3(12,2,NN),256,0,stream>>>(Axin+8,A0S, Wstat,320,(size_t)G3*320,
        TI, 10, biasS,G3, Sbuf,G3, 0);
    k_init_state<<<NN,256,0,stream>>>(P[0],P[3],flags,Axin,qcv,out_xt);

    for (int s=0; s<PH; ++s){
      k_fgemm<<<dim3(16,2,NN),256,0,stream>>>(hbuf,Axin,Wpack,TI,Sbuf,bhh2F,Cbig);
      k_gru<<<dim3(2,BB),256,0,stream>>>(Cbig,Gns,hbuf);
      k_mgemm<0,0,0><<<dim3(2,2,NN),256,0,stream>>>(Cbig,NC2, Wqcb,512,(size_t)256*512,
          TI, 16, bqcF,256, Cbig,NC2, 512);
      k_out<<<(NN*BB)/4,256,0,stream>>>(Cbig,Gqs,Gcs,TI,flags,P[21],P[22],P[23],P[24],
          qcv,Axin,out_dq,out_cov,s);
    }
  } else {
    // ---- Path B: R11 pipeline (proven) ----
    k_cvt_f<<<(NN*G3+255)/256,256,0,stream>>>(P[11], bihF, NN*G3, flags);
    k_cvt_f<<<(NN*G3+255)/256,256,0,stream>>>(P[12], bhhF, NN*G3, flags);
    k_cvt_wpadg<<<(4*G3*A0S+255)/256,256,0,stream>>>(P[9], Wihb, 4*G3, 328, A0S, flags);
    k_cvt_w<<<(4*G3*512+255)/256,256,0,stream>>>(P[10], Whhb, 4*G3*512, flags);

    k_ngemm<1><<<dim3(HID/8,NN),256,0,stream>>>(Axin,A0S, P[6],328,(size_t)512*328,
        P[7],512, TI,flags, 328, hbuf,512);
    k_mix_init<<<dim3(2,BB),256,0,stream>>>(hbuf,G0s,hbuf);
    k_init_state<<<NN,256,0,stream>>>(P[0],P[3],flags,Axin,qcv,out_xt);

    for (int s=0; s<PH; ++s){
      k_mgemm<0,0,0><<<dim3(12,2,NN),256,0,stream>>>(Axin,A0S, Wihb,A0S,(size_t)G3*A0S,
          TI, 11, bihF,G3, Cbig,NC2, 0);
      k_mgemm<1,1,0><<<dim3(12,2,NN),256,0,stream>>>(hbuf,HID, Whhb,512,(size_t)G3*512,
          TI, 16, bhhF,G3, Cbig,NC2, 0);
      k_gru<<<dim3(2,BB),256,0,stream>>>(Cbig,Gns,hbuf);
      k_mgemm<0,0,0><<<dim3(2,2,NN),256,0,stream>>>(Cbig,NC2, Wqcb,512,(size_t)256*512,
          TI, 16, bqcF,256, Cbig,NC2, 512);
      k_out<<<(NN*BB)/4,256,0,stream>>>(Cbig,Gqs,Gcs,TI,flags,P[21],P[22],P[23],P[24],
          qcv,Axin,out_dq,out_cov,s);
    }
  }
}

// Round 13
// 1155.176 us; speedup vs baseline: 6.6654x; 1.1409x over previous
//
#include <hip/hip_runtime.h>

typedef unsigned short u16;
typedef __bf16 bf16_t;
typedef bf16_t bf16x8 __attribute__((ext_vector_type(8)));
typedef float f32x4 __attribute__((ext_vector_type(4)));
typedef long long i64;

#define NN   21
#define BB   256
#define HID  512
#define G3   1536
#define NC2  2048
#define A0S  352
#define PH   12
#define WSK  516
#define LK   40    // LDS row stride (32+8 pad) bf16 elems
#define KP   544   // packed gate K (512 h + 8 x + 24 pad)

__device__ __forceinline__ u16 f2b(float f){ bf16_t b = (bf16_t)f; return __builtin_bit_cast(u16, b); }
__device__ __forceinline__ float b2f(u16 u){ bf16_t b = __builtin_bit_cast(bf16_t, u); return (float)b; }
__device__ __forceinline__ bf16_t fb(float f){ return (bf16_t)f; }
__device__ __forceinline__ float sigm(float x){ return 1.0f / (1.0f + __expf(-x)); }
__device__ __forceinline__ float ftanh(float x){
  x = fminf(15.0f, fmaxf(-15.0f, x));
  float e = __expf(2.0f * x);
  return (e - 1.0f) / (e + 1.0f);
}
__device__ __forceinline__ float ldf(const void* p, size_t idx, int mode){
  if (mode == 2) return b2f(((const u16*)p)[idx]);
  if (mode == 1) return (float)((const double*)p)[idx];
  return ((const float*)p)[idx];
}

__global__ void k_fill(float* out, int n, float c){
  int idx = blockIdx.x*256 + threadIdx.x;
  if (idx < n) out[idx] = c;
}

__global__ void k_detect(const void* w0raw, const void* traw, int* flags){
  if (threadIdx.x != 0 || blockIdx.x != 0) return;
  const float*  v32 = (const float*)w0raw;
  const double* v64 = (const double*)w0raw;
  const u16*    vbf = (const u16*)w0raw;
  int c32 = 0, c64 = 0, cbf = 0;
  for (int i = 0; i < 64; ++i){
    float a32 = fabsf(v32[i]);
    if (a32 >= 1e-8f && a32 <= 1e4f) ++c32;
    double a64 = fabs(v64[i]);
    if (a64 >= 1e-8 && a64 <= 1e4) ++c64;
    float abf = fabsf(b2f(vbf[i]));
    if (abf >= 1e-8f && abf <= 1e4f) ++cbf;
  }
  int mode;
  if (cbf >= 60 && c32 < 48) mode = 2;
  else if (c32 >= 48)        mode = 0;
  else if (c64 >= 48)        mode = 1;
  else                       mode = 2;
  flags[0] = mode;
  const int* tw = (const int*)traw;
  int ok64 = 1;
  for (int i = 0; i < NN; ++i){
    unsigned lo = (unsigned)tw[2*i];
    int hi = tw[2*i+1];
    if (hi != 0 || lo >= 4u) { ok64 = 0; break; }
  }
  flags[1] = ok64;
}
__global__ void k_cvt_i(const void* src, int* dst, int n, const int* flags){
  int idx = threadIdx.x;
  if (idx >= n) return;
  if (flags[1]) dst[idx] = (int)((const i64*)src)[idx];
  else          dst[idx] = ((const int*)src)[idx];
}
__global__ void k_cvt_f(const void* src, float* dst, int n, const int* flags){
  int idx = blockIdx.x*256 + threadIdx.x;
  if (idx < n) dst[idx] = ldf(src, idx, flags[0]);
}
__global__ void k_cvt_wpadg(const void* W, u16* dst, int rows, int srcK, int dstK, const int* flags){
  int idx = blockIdx.x*256 + threadIdx.x;
  if (idx >= rows*dstK) return;
  int k = idx % dstK, r = idx / dstK;
  dst[idx] = (k < srcK) ? f2b(ldf(W, (size_t)r*srcK + k, flags[0])) : (u16)0;
}
__global__ void k_cvt_w(const void* W, u16* dst, int n, const int* flags){
  int idx = blockIdx.x*256 + threadIdx.x;
  if (idx < n) dst[idx] = f2b(ldf(W, idx, flags[0]));
}
__global__ void k_cvt_wstat(const void* Wih, u16* dst, const int* flags){
  int idx = blockIdx.x*256 + threadIdx.x;
  if (idx >= 4*G3*320) return;
  int k2 = idx % 320, tg = idx / 320;
  dst[idx] = f2b(ldf(Wih, (size_t)tg*328 + 8 + k2, flags[0]));
}
// Wpack[t][g'][k] (2048 x 544):
//  g'<1024: [Whh[g'] | Wih[g'][0:8] | 0]; 1024..1535: [0 | Wih[g'][0:8] | 0]; 1536..2047: [Whh[g'-512] | 0]
__global__ void k_pack_wpack(const void* Whh, const void* Wih, u16* Wp, const int* flags){
  int idx = blockIdx.x*256 + threadIdx.x;
  if (idx >= 4*NC2*KP) return;
  const int md = flags[0];
  int k  = idx % KP;
  int tg = idx / KP;
  int g  = tg % NC2;
  int t  = tg / NC2;
  float v = 0.f;
  if (g < 1024){
    if (k < 512)             v = ldf(Whh, ((size_t)(t*G3 + g) << 9) + k, md);
    else if (k < 520)        v = ldf(Wih, (size_t)(t*G3 + g)*328 + (k - 512), md);
  } else if (g < 1536){
    if (k >= 512 && k < 520) v = ldf(Wih, (size_t)(t*G3 + g)*328 + (k - 512), md);
  } else {
    if (k < 512)             v = ldf(Whh, ((size_t)(t*G3 + (g - 512)) << 9) + k, md);
  }
  Wp[idx] = f2b(v);
}
__global__ void k_cvt_wqc(const void* Wq, const void* Wc, u16* dst, const int* flags){
  int idx = blockIdx.x*256 + threadIdx.x;
  if (idx >= 4*256*512) return;
  int k  = idx & 511;
  int tg = idx >> 9;
  int g  = tg & 255;
  int t  = tg >> 8;
  const int md = flags[0];
  dst[idx] = f2b((g < 128) ? ldf(Wq, ((size_t)(t*128 + g) << 9) + k, md)
                           : ldf(Wc, ((size_t)(t*128 + (g-128)) << 9) + k, md));
}
__global__ void k_bqc(const void* bq, const void* bc, float* bqc, const int* flags){
  int idx = blockIdx.x*256 + threadIdx.x;
  if (idx >= NN*256) return;
  int o = idx & 255; int n = idx >> 8;
  const int md = flags[0];
  bqc[idx] = (o < 128) ? ldf(bq,(size_t)n*128+o,md) : ldf(bc,(size_t)n*128+(o-128),md);
}
__global__ void k_biasS(const void* bih, const void* bhh, float* biasS, float* bhh2, const int* flags){
  int idx = blockIdx.x*256 + threadIdx.x;
  if (idx >= NN*G3) return;
  const int md = flags[0];
  int g = idx % G3;
  float v = ldf(bih, idx, md);
  if (g < 1024) v += ldf(bhh, idx, md);
  biasS[idx] = v;
  if (g >= 1024){
    int n = idx / G3;
    bhh2[n*512 + (g - 1024)] = ldf(bhh, idx, md);
  }
}

__global__ void k_prep_G(const void* G0, const void* Grnn, const void* GA,
                         const void* Gq, const void* Gc, const int* flags,
                         float* G0s, float* Gns, float* Gqs, float* Gcs){
  int tid = threadIdx.x;
  if (tid >= 84) return;
  const int md = flags[0];
  int mat = tid / 21, row = tid % 21;
  const void* src = mat==0 ? G0 : mat==1 ? Grnn : mat==2 ? Gq : Gc;
  float* dst      = mat==0 ? G0s : mat==1 ? Gns : mat==2 ? Gqs : Gcs;
  float s = 0.f;
  for (int m=0;m<21;++m) s += fabsf(ldf(src,row*21+m,md));
  s = fmaxf(s, 1e-12f);
  for (int m=0;m<21;++m){
    float v = ldf(src,row*21+m,md) / s;
    if (mat==1) v += ldf(GA,row*21+m,md);
    dst[row*21+m] = v;
  }
}

__global__ void k_build_A0(const void* x, const void* z, const void* hin,
                           const int* flags, u16* A0){
  int idx = blockIdx.x*256 + threadIdx.x;
  if (idx >= NN*BB*A0S) return;
  const int md = flags[0];
  int k  = idx % A0S;
  int nb = idx / A0S;
  int b  = nb % BB;
  int n  = nb / BB;
  float v = 0.f;
  if (k < 8)        v = ldf(x, ((size_t)(b*2 + 0)*NN + n)*8 + k, md);
  else if (k < 72)  v = ldf(z, ((size_t)b*NN + n)*64 + (k - 8), md);
  else if (k < 328) v = ldf(hin, ((size_t)b*NN + n)*256 + (k - 72), md);
  A0[idx] = f2b(v);
}

__global__ void k_init_state(const void* x, const void* qt, const int* flags,
                             u16* Axin, float* qc, float* out2){
  int b = threadIdx.x; int n = blockIdx.x;
  const int md = flags[0];
  for (int f=0; f<8; ++f){
    float raw = ldf(x, ((size_t)(b*2 + 1)*NN + n)*8 + f, md);
    Axin[(size_t)(n*BB + b)*A0S + f] = f2b(raw);
    out2[(b*NN + n)*8 + f] = raw;
  }
  for (int c=0; c<4; ++c) qc[(n*BB + b)*4 + c] = ldf(qt, ((size_t)b*NN + n)*4 + c, md);
}

// ---------------- naive GEMM (Path B W0 init) ----------------
template<int ABF>
__global__ __launch_bounds__(256)
void k_ngemm(const void* __restrict__ A_, int sA,
             const void* __restrict__ W_, int sW, size_t tstride,
             const void* __restrict__ bias_, int biasN,
             const int* __restrict__ T, const int* __restrict__ flags, int K,
             float* __restrict__ C, int Nc)
{
  __shared__ float Ws[8*WSK];
  const int node = blockIdx.y;
  const int g0   = blockIdx.x*8;
  const int tid  = threadIdx.x;
  const int t    = T[node];
  const int md   = flags[0];
  for (int idx = tid; idx < 8*K; idx += 256){
    int gg = idx / K, kk = idx - gg*K;
    Ws[gg*WSK + kk] = ldf(W_, (size_t)t*tstride + (size_t)(g0+gg)*sW + kk, md);
  }
  __syncthreads();
  const int b = tid;
  const float* Af = (const float*)A_;
  const u16*   Ab = (const u16*)A_;
  float acc[8];
  #pragma unroll
  for (int gg=0; gg<8; ++gg) acc[gg] = ldf(bias_, (size_t)node*biasN + g0 + gg, md);
  const size_t abase = (size_t)(node*BB + b)*sA;
  for (int k=0; k<K; ++k){
    const float av = ABF ? b2f(Ab[abase + k]) : Af[abase + k];
    #pragma unroll
    for (int gg=0; gg<8; ++gg) acc[gg] += av * Ws[gg*WSK + k];
  }
  #pragma unroll
  for (int gg=0; gg<8; ++gg)
    C[(size_t)(node*BB + b)*Nc + g0 + gg] = acc[gg];
}

// ---------------- MFMA GEMM 128x128 (Path B, proven) ----------------
template<int AMODE, int GRUH, int FOUT>
__global__ __launch_bounds__(256,2)
void k_mgemm(const void* __restrict__ A_, int sA,
             const u16* __restrict__ W, int sW, size_t tstride,
             const int* __restrict__ T, int nchunks,
             const float* __restrict__ bias, int biasN,
             void* __restrict__ C_, int Nc, int goff)
{
  __shared__ u16 As[128*LK];
  __shared__ u16 Bs[128*LK];
  const int ntile = blockIdx.x, mtile = blockIdx.y, node = blockIdx.z;
  const int tid = threadIdx.x;
  const int t = T[node];
  const int lane = tid & 63, wv = tid >> 6;
  const int wm = wv & 1, wn = wv >> 1;
  const int l16 = lane & 15, quad = lane >> 4;
  const int row0 = mtile*128, col0 = ntile*128;
  u16* Cb = (u16*)C_;
  float* Cf = (float*)C_;

  f32x4 acc[4][4];
  #pragma unroll
  for (int mt=0; mt<4; ++mt)
  #pragma unroll
  for (int nt=0; nt<4; ++nt){
    const int col = col0 + wn*64 + nt*16 + l16;
    const float bv = bias[node*biasN + col];
    if (GRUH && ntile < 8){
      #pragma unroll
      for (int r=0;r<4;++r){
        const int row = row0 + wm*64 + mt*16 + quad*4 + r;
        acc[mt][nt][r] = bv + b2f(Cb[(size_t)(node*BB + row)*Nc + col]);
      }
    } else {
      #pragma unroll
      for (int r=0;r<4;++r) acc[mt][nt][r] = bv;
    }
  }

  const int sr = tid >> 1, seg = tid & 1;
  for (int kc = 0; kc < nchunks; ++kc){
    const int k0 = kc*32 + seg*16;
    if (AMODE == 0){
      const u16* srcA = (const u16*)A_ + (size_t)(node*BB + row0 + sr)*sA + k0;
      *(uint4*)&As[sr*LK + seg*16]     = *(const uint4*)srcA;
      *(uint4*)&As[sr*LK + seg*16 + 8] = *(const uint4*)(srcA + 8);
    } else {
      const float* srcA = (const float*)A_ + (size_t)(node*BB + row0 + sr)*sA + k0;
      float4 f0 = *(const float4*)(srcA);
      float4 f1 = *(const float4*)(srcA+4);
      float4 f2 = *(const float4*)(srcA+8);
      float4 f3 = *(const float4*)(srcA+12);
      bf16x8 v0, v1;
      v0[0]=fb(f0.x); v0[1]=fb(f0.y); v0[2]=fb(f0.z); v0[3]=fb(f0.w);
      v0[4]=fb(f1.x); v0[5]=fb(f1.y); v0[6]=fb(f1.z); v0[7]=fb(f1.w);
      v1[0]=fb(f2.x); v1[1]=fb(f2.y); v1[2]=fb(f2.z); v1[3]=fb(f2.w);
      v1[4]=fb(f3.x); v1[5]=fb(f3.y); v1[6]=fb(f3.z); v1[7]=fb(f3.w);
      *(bf16x8*)&As[sr*LK + seg*16]     = v0;
      *(bf16x8*)&As[sr*LK + seg*16 + 8] = v1;
    }
    {
      const u16* srcB = W + (size_t)t*tstride + (size_t)(col0 + sr)*sW + k0;
      *(uint4*)&Bs[sr*LK + seg*16]     = *(const uint4*)srcB;
      *(uint4*)&Bs[sr*LK + seg*16 + 8] = *(const uint4*)(srcB + 8);
    }
    __syncthreads();
    bf16x8 af[4], bfr[4];
    #pragma unroll
    for (int mt=0; mt<4; ++mt) af[mt]  = *(const bf16x8*)&As[(wm*64 + mt*16 + l16)*LK + quad*8];
    #pragma unroll
    for (int nt=0; nt<4; ++nt) bfr[nt] = *(const bf16x8*)&Bs[(wn*64 + nt*16 + l16)*LK + quad*8];
    #pragma unroll
    for (int mt=0; mt<4; ++mt)
    #pragma unroll
    for (int nt=0; nt<4; ++nt)
      acc[mt][nt] = __builtin_amdgcn_mfma_f32_16x16x32_bf16(af[mt], bfr[nt], acc[mt][nt], 0, 0, 0);
    __syncthreads();
  }

  #pragma unroll
  for (int mt=0; mt<4; ++mt)
  #pragma unroll
  for (int nt=0; nt<4; ++nt){
    const int col = col0 + wn*64 + nt*16 + l16;
    const int dcol = GRUH ? ((ntile < 8) ? col : col + 512) : col + goff;
    #pragma unroll
    for (int r=0;r<4;++r){
      const int row = row0 + wm*64 + mt*16 + quad*4 + r;
      if (FOUT) Cf[(size_t)(node*BB + row)*Nc + dcol] = acc[mt][nt][r];
      else      Cb[(size_t)(node*BB + row)*Nc + dcol] = f2b(acc[mt][nt][r]);
    }
  }
}

// ---------------- tiled MFMA GEMM 128col x 64row (Path A) ----------------
// A bf16 [node][BB][sA]; W bf16 [t][cols][sW]; C stride Nc (+goff), bias fp32.
template<int FOUT>
__global__ __launch_bounds__(256,4)
void k_tg(const u16* __restrict__ A, int sA,
          const u16* __restrict__ W, int sW, size_t tstride,
          const int* __restrict__ T, int nchunks,
          const float* __restrict__ bias, int biasN,
          void* __restrict__ C_, int Nc, int goff)
{
  __shared__ u16 As[64*LK];
  __shared__ u16 Bs[128*LK];
  const int ntile = blockIdx.x, mtile = blockIdx.y, node = blockIdx.z;
  const int tid = threadIdx.x;
  const int t = T[node];
  const int lane = tid & 63, wv = tid >> 6;
  const int wm = wv & 1, wn = wv >> 1;
  const int l16 = lane & 15, quad = lane >> 4;
  const int row0 = mtile*64, col0 = ntile*128;
  u16* Cb = (u16*)C_; float* Cf = (float*)C_;

  f32x4 acc[2][4];
  #pragma unroll
  for (int mt=0; mt<2; ++mt)
  #pragma unroll
  for (int nt=0; nt<4; ++nt){
    const float bv = bias[node*biasN + col0 + wn*64 + nt*16 + l16];
    #pragma unroll
    for (int r=0;r<4;++r) acc[mt][nt][r] = bv;
  }

  const int arow = tid >> 2, aseg = tid & 3;
  const int brow = tid >> 1, bseg = tid & 1;
  for (int kc = 0; kc < nchunks; ++kc){
    *(uint4*)&As[arow*LK + aseg*8] =
      *(const uint4*)(A + (size_t)(node*BB + row0 + arow)*sA + kc*32 + aseg*8);
    {
      const u16* srcB = W + (size_t)t*tstride + (size_t)(col0 + brow)*sW + kc*32 + bseg*16;
      *(uint4*)&Bs[brow*LK + bseg*16]     = *(const uint4*)srcB;
      *(uint4*)&Bs[brow*LK + bseg*16 + 8] = *(const uint4*)(srcB + 8);
    }
    __syncthreads();
    bf16x8 af[2], bfr[4];
    #pragma unroll
    for (int mt=0; mt<2; ++mt) af[mt]  = *(const bf16x8*)&As[(wm*32 + mt*16 + l16)*LK + quad*8];
    #pragma unroll
    for (int nt=0; nt<4; ++nt) bfr[nt] = *(const bf16x8*)&Bs[(wn*64 + nt*16 + l16)*LK + quad*8];
    #pragma unroll
    for (int mt=0; mt<2; ++mt)
    #pragma unroll
    for (int nt=0; nt<4; ++nt)
      acc[mt][nt] = __builtin_amdgcn_mfma_f32_16x16x32_bf16(af[mt], bfr[nt], acc[mt][nt], 0, 0, 0);
    __syncthreads();
  }

  #pragma unroll
  for (int mt=0; mt<2; ++mt)
  #pragma unroll
  for (int nt=0; nt<4; ++nt){
    const int col = col0 + wn*64 + nt*16 + l16 + goff;
    #pragma unroll
    for (int r=0;r<4;++r){
      const int row = row0 + wm*32 + mt*16 + quad*4 + r;
      if (FOUT) Cf[(size_t)(node*BB + row)*Nc + col] = acc[mt][nt][r];
      else      Cb[(size_t)(node*BB + row)*Nc + col] = f2b(acc[mt][nt][r]);
    }
  }
}

// ---------------- fused gate GEMM 128x64 (Path A) ----------------
// A: k<512 from hb (bf16, stride HID); kc==16: 8 x_c bf16 from Ax. C-init Sbuf/bhh2.
__global__ __launch_bounds__(256,4)
void k_fg(const u16* __restrict__ hb, const u16* __restrict__ Ax,
          const u16* __restrict__ Wp, const int* __restrict__ T,
          const u16* __restrict__ Sbuf, const float* __restrict__ bhh2,
          u16* __restrict__ C)
{
  __shared__ u16 As[64*LK];
  __shared__ u16 Bs[128*LK];
  const int ntile = blockIdx.x, mtile = blockIdx.y, node = blockIdx.z;
  const int tid = threadIdx.x;
  const int t = T[node];
  const int lane = tid & 63, wv = tid >> 6;
  const int wm = wv & 1, wn = wv >> 1;
  const int l16 = lane & 15, quad = lane >> 4;
  const int row0 = mtile*64, col0 = ntile*128;

  f32x4 acc[2][4];
  #pragma unroll
  for (int mt=0; mt<2; ++mt)
  #pragma unroll
  for (int nt=0; nt<4; ++nt){
    const int col = col0 + wn*64 + nt*16 + l16;
    #pragma unroll
    for (int r=0;r<4;++r){
      const int row = row0 + wm*32 + mt*16 + quad*4 + r;
      acc[mt][nt][r] = (col < 1536)
        ? b2f(Sbuf[(size_t)(node*BB + row)*G3 + col])
        : bhh2[node*512 + (col - 1536)];
    }
  }

  int kc0 = 0, kc1 = 17;
  if (ntile >= 8 && ntile < 12) kc0 = 16;       // ic: only x chunk
  else if (ntile >= 12)         kc1 = 16;       // hc2: no x chunk

  const int arow = tid >> 2, aseg = tid & 3;
  const int brow = tid >> 1, bseg = tid & 1;
  for (int kc = kc0; kc < kc1; ++kc){
    if (kc < 16){
      *(uint4*)&As[arow*LK + aseg*8] =
        *(const uint4*)(hb + (size_t)(node*BB + row0 + arow)*HID + kc*32 + aseg*8);
    } else {
      uint4 zz; zz.x = zz.y = zz.z = zz.w = 0u;
      uint4 u0 = zz;
      if (aseg == 0) u0 = *(const uint4*)(Ax + (size_t)(node*BB + row0 + arow)*A0S);
      *(uint4*)&As[arow*LK + aseg*8] = u0;
    }
    {
      const u16* srcB = Wp + (size_t)t*NC2*KP + (size_t)(col0 + brow)*KP + kc*32 + bseg*16;
      *(uint4*)&Bs[brow*LK + bseg*16]     = *(const uint4*)srcB;
      *(uint4*)&Bs[brow*LK + bseg*16 + 8] = *(const uint4*)(srcB + 8);
    }
    __syncthreads();
    bf16x8 af[2], bfr[4];
    #pragma unroll
    for (int mt=0; mt<2; ++mt) af[mt]  = *(const bf16x8*)&As[(wm*32 + mt*16 + l16)*LK + quad*8];
    #pragma unroll
    for (int nt=0; nt<4; ++nt) bfr[nt] = *(const bf16x8*)&Bs[(wn*64 + nt*16 + l16)*LK + quad*8];
    #pragma unroll
    for (int mt=0; mt<2; ++mt)
    #pragma unroll
    for (int nt=0; nt<4; ++nt)
      acc[mt][nt] = __builtin_amdgcn_mfma_f32_16x16x32_bf16(af[mt], bfr[nt], acc[mt][nt], 0, 0, 0);
    __syncthreads();
  }

  #pragma unroll
  for (int mt=0; mt<2; ++mt)
  #pragma unroll
  for (int nt=0; nt<4; ++nt){
    const int col = col0 + wn*64 + nt*16 + l16;
    #pragma unroll
    for (int r=0;r<4;++r){
      const int row = row0 + wm*32 + mt*16 + quad*4 + r;
      C[(size_t)(node*BB + row)*NC2 + col] = f2b(acc[mt][nt][r]);
    }
  }
}

// ---------------- mixing / GRU / head ----------------

// HB=1: h stored bf16; HB=0: fp32
template<int HB>
__global__ __launch_bounds__(256)
void k_mix_init(const float* C0, const float* G0s, void* h_){
  __shared__ float Gs[441];
  const int tid = threadIdx.x;
  for (int i = tid; i < 441; i += 256) Gs[i] = G0s[i];
  __syncthreads();
  const int b = blockIdx.y;
  const int j = blockIdx.x*256 + tid;
  float P[21];
  #pragma unroll
  for (int m=0;m<21;++m) P[m] = C0[(size_t)(m*BB + b)*HID + j];
  float R[21];
  for (int n=0;n<21;++n){
    float s = 0.f;
    #pragma unroll
    for (int m=0;m<21;++m) s += Gs[n*21+m]*P[m];
    R[n] = s;
  }
  for (int n=0;n<21;++n){
    const size_t hi = (size_t)(n*BB + b)*HID + j;
    if (HB) ((u16*)h_)[hi] = f2b(R[n]);
    else    ((float*)h_)[hi] = R[n];
  }
}

template<int HB>
__global__ __launch_bounds__(256)
void k_gru(u16* __restrict__ Cb, const float* __restrict__ Gns, void* __restrict__ h_){
  __shared__ float Gs[441];
  const int tid = threadIdx.x;
  for (int i = tid; i < 441; i += 256) Gs[i] = Gns[i];
  __syncthreads();
  const int b = blockIdx.y;
  const int j = blockIdx.x*256 + tid;
  float P1[21], P2[21], P3[21], P4[21];
  #pragma unroll
  for (int m=0;m<21;++m){
    const size_t base = (size_t)(m*BB + b)*NC2 + j;
    P1[m] = b2f(Cb[base]);
    P2[m] = b2f(Cb[base + 512]);
    P3[m] = b2f(Cb[base + 1024]);
    P4[m] = b2f(Cb[base + 1536]);
  }
  for (int n=0;n<21;++n){
    float s1=0.f, s2=0.f, s3=0.f, s4=0.f;
    #pragma unroll
    for (int m=0;m<21;++m){
      const float g = Gs[n*21+m];
      s1 += g*P1[m]; s2 += g*P2[m]; s3 += g*P3[m]; s4 += g*P4[m];
    }
    const size_t hi = (size_t)(n*BB + b)*HID + j;
    const float hc = HB ? b2f(((u16*)h_)[hi]) : ((float*)h_)[hi];
    const float r  = sigm(s1);
    const float zg = sigm(s2);
    const float nn = ftanh(s3 + r*s4);
    const float hn = (1.f - zg)*nn + zg*hc;
    if (HB) ((u16*)h_)[hi] = f2b(hn);
    else    ((float*)h_)[hi] = hn;
    Cb[(size_t)(n*BB + b)*NC2 + j] = f2b(ftanh(hn));   // y
  }
}

__global__ __launch_bounds__(256)
void k_out(const u16* __restrict__ Cbig, const float* __restrict__ Gqs, const float* __restrict__ Gcs,
           const int* __restrict__ T, const int* __restrict__ flags,
           const void* __restrict__ W3, const void* __restrict__ b3,
           const void* __restrict__ W6, const void* __restrict__ b6,
           float* __restrict__ qc, u16* __restrict__ Axin,
           float* __restrict__ out_dq, float* __restrict__ out_cov, int s)
{
  const int tid = threadIdx.x;
  const int w = blockIdx.x*4 + (tid >> 6);
  const int lane = tid & 63;
  const int b = w / 21, n = w % 21;
  const int t = T[n];
  const int md = flags[0];
  float aq1=0.f, aq2=0.f, ac1=0.f, ac2=0.f;
  #pragma unroll
  for (int m=0;m<21;++m){
    const u16* c = Cbig + (size_t)(m*BB + b)*NC2 + 512;
    const float gq = Gqs[n*21+m], gc = Gcs[n*21+m];
    aq1 += gq*b2f(c[lane]);       aq2 += gq*b2f(c[lane+64]);
    ac1 += gc*b2f(c[lane+128]);   ac2 += gc*b2f(c[lane+192]);
  }
  const float ys1 = ftanh(aq1), ys2 = ftanh(aq2);
  const float yc1 = ftanh(ac1), yc2 = ftanh(ac2);
  float red[9];
  #pragma unroll
  for (int a=0;a<3;++a)
    red[a] = ys1*ldf(W3,(size_t)(t*3+a)*128 + lane,md) + ys2*ldf(W3,(size_t)(t*3+a)*128 + lane + 64,md);
  #pragma unroll
  for (int a=0;a<6;++a)
    red[3+a] = yc1*ldf(W6,(size_t)(t*6+a)*128 + lane,md) + yc2*ldf(W6,(size_t)(t*6+a)*128 + lane + 64,md);
  #pragma unroll
  for (int i=0;i<9;++i){
    red[i] += __shfl_xor(red[i], 32);
    red[i] += __shfl_xor(red[i], 16);
    red[i] += __shfl_xor(red[i], 8);
    red[i] += __shfl_xor(red[i], 4);
    red[i] += __shfl_xor(red[i], 2);
    red[i] += __shfl_xor(red[i], 1);
  }
  const float d0 = red[0] + ldf(b3,(size_t)n*3+0,md);
  const float d1 = red[1] + ldf(b3,(size_t)n*3+1,md);
  const float d2 = red[2] + ldf(b3,(size_t)n*3+2,md);
  const float theta = sqrtf(d0*d0 + d1*d1 + d2*d2);
  const float wq = cosf(0.5f*theta);
  const float kq = (theta > 1e-8f) ? (sinf(0.5f*theta) / fmaxf(theta, 1e-8f)) : 0.5f;
  const float x1 = kq*d0, y1 = kq*d1, z1 = kq*d2;
  if (lane == 0){
    float* q = qc + (size_t)(n*BB + b)*4;
    const float qw=q[0], qx=q[1], qy=q[2], qz=q[3];
    const float nw = wq*qw - (x1*qx + y1*qy + z1*qz);
    const float nx = wq*qx + qw*x1 + (y1*qz - z1*qy);
    const float ny = wq*qy + qw*y1 + (z1*qx - x1*qz);
    const float nz = wq*qz + qw*z1 + (x1*qy - y1*qx);
    q[0]=nw; q[1]=nx; q[2]=ny; q[3]=nz;
    u16* ax = Axin + (size_t)(n*BB + b)*A0S;
    ax[0]=f2b(nw); ax[1]=f2b(nx); ax[2]=f2b(ny); ax[3]=f2b(nz);
    ax[4]=f2b(wq); ax[5]=f2b(x1); ax[6]=f2b(y1); ax[7]=f2b(z1);
    float* od = out_dq + (size_t)((b*PH + s)*NN + n)*4;
    od[0]=wq; od[1]=x1; od[2]=y1; od[3]=z1;
    float* oc = out_cov + (size_t)((b*PH + s)*NN + n)*6;
    for (int a=0;a<6;++a) oc[a] = red[3+a] + ldf(b6,(size_t)n*6+a,md);
  }
}

// ---------------- launch ----------------

extern "C" void kernel_launch(void* const* d_in, const int* in_sizes, int n_in,
                              void* d_out, int out_size, void* d_ws, size_t ws_size,
                              hipStream_t stream)
{
  const void* P[25];
  {
    int j = 0;
    for (int i = 0; i < 25; ++i){
      if (i == 5){ P[i] = nullptr; continue; }
      while (j < n_in && in_sizes[j] == 1) ++j;
      P[i] = (j < n_in) ? d_in[j++] : nullptr;
    }
  }

  float* out_dq  = (float*)d_out;
  float* out_cov = out_dq  + (size_t)BB*PH*NN*4;
  float* out_xt  = out_cov + (size_t)BB*PH*NN*6;

  char* wsb = (char*)d_ws;
  size_t off = 0;
  auto carve = [&](size_t bytes)->void*{
    void* p = wsb + off;
    off = (off + bytes + 255) & ~(size_t)255;
    return p;
  };

  // common
  int*   flags = (int*)  carve(2*4);
  int*   TI    = (int*)  carve(NN*4);
  float* G0s   = (float*)carve(441*4);
  float* Gns   = (float*)carve(441*4);
  float* Gqs   = (float*)carve(441*4);
  float* Gcs   = (float*)carve(441*4);
  float* bqcF  = (float*)carve((size_t)NN*256*4);
  float* qcv   = (float*)carve((size_t)NN*BB*4*4);
  u16*   Axin  = (u16*)  carve((size_t)NN*BB*A0S*2);
  u16*   Wqcb  = (u16*)  carve((size_t)4*256*512*2);
  float* hbuf  = (float*)carve((size_t)NN*BB*HID*4);   // B: fp32 h; A: bf16 h (low half)
  u16*   Cbig  = (u16*)  carve((size_t)NN*BB*NC2*2);

  // Path A extras
  size_t offA = off;
  auto carveA = [&](size_t bytes)->void*{
    void* p = wsb + offA;
    offA = (offA + bytes + 255) & ~(size_t)255;
    return p;
  };
  float* b0F   = (float*)carveA((size_t)NN*HID*4);
  float* biasS = (float*)carveA((size_t)NN*G3*4);
  float* bhh2F = (float*)carveA((size_t)NN*512*4);
  u16*   W0b   = (u16*)  carveA((size_t)4*HID*A0S*2);
  u16*   Wstat = (u16*)  carveA((size_t)4*G3*320*2);
  u16*   Wpack = (u16*)  carveA((size_t)4*NC2*KP*2);
  u16*   Sbuf  = (u16*)  carveA((size_t)NN*BB*G3*2);
  const size_t NEED_A = offA;

  // Path B extras
  size_t offB = off;
  auto carveB = [&](size_t bytes)->void*{
    void* p = wsb + offB;
    offB = (offB + bytes + 255) & ~(size_t)255;
    return p;
  };
  float* bihF  = (float*)carveB((size_t)NN*G3*4);
  float* bhhF  = (float*)carveB((size_t)NN*G3*4);
  u16*   Wihb  = (u16*)  carveB((size_t)4*G3*A0S*2);
  u16*   Whhb  = (u16*)  carveB((size_t)4*G3*512*2);
  const size_t NEED_B = offB;

  if (ws_size < NEED_B){
    float code = 150.0f + (float)(ws_size >> 23);
    k_fill<<<(out_size+255)/256,256,0,stream>>>((float*)d_out, out_size, code);
    return;
  }

  // common prep
  k_detect<<<1,64,0,stream>>>(P[6], P[4], flags);
  k_cvt_i<<<1,64,0,stream>>>(P[4], TI, NN, flags);
  k_prep_G<<<1,128,0,stream>>>(P[8],P[13],P[14],P[17],P[20],flags, G0s,Gns,Gqs,Gcs);
  k_bqc<<<(NN*256+255)/256,256,0,stream>>>(P[16],P[19],bqcF,flags);
  k_build_A0<<<(NN*BB*A0S+255)/256,256,0,stream>>>(P[0],P[2],P[1],flags,Axin);
  k_cvt_wqc<<<(4*256*512+255)/256,256,0,stream>>>(P[15],P[18],Wqcb,flags);

  if (ws_size >= NEED_A){
    // ---- Path A: fused pipeline, bf16 h, 128x64 tiles ----
    u16* hb = (u16*)hbuf;               // bf16 h state
    float* C0f = (float*)Cbig;          // one-shot fp32 C0 (11 MB of 22)

    k_cvt_f<<<(NN*HID+255)/256,256,0,stream>>>(P[7], b0F, NN*HID, flags);
    k_biasS<<<(NN*G3+255)/256,256,0,stream>>>(P[11],P[12],biasS,bhh2F,flags);
    k_cvt_wpadg<<<(4*HID*A0S+255)/256,256,0,stream>>>(P[6], W0b, 4*HID, 328, A0S, flags);
    k_cvt_wstat<<<(4*G3*320+255)/256,256,0,stream>>>(P[9], Wstat, flags);
    k_pack_wpack<<<(4*NC2*KP+255)/256,256,0,stream>>>(P[10], P[9], Wpack, flags);

    // C0 = Axin(x_{t-1}) . W0^T + b0  (fp32 into Cbig alias)
    k_tg<1><<<dim3(4,4,NN),256,0,stream>>>(Axin,A0S, W0b,A0S,(size_t)HID*A0S,
        TI, 11, b0F,HID, C0f,HID, 0);
    k_mix_init<1><<<dim3(2,BB),256,0,stream>>>(C0f,G0s,hb);
    // Sbuf = h_z . Wih[:,8:]^T + biasS
    k_tg<0><<<dim3(12,4,NN),256,0,stream>>>(Axin+8,A0S, Wstat,320,(size_t)G3*320,
        TI, 10, biasS,G3, Sbuf,G3, 0);
    k_init_state<<<NN,256,0,stream>>>(P[0],P[3],flags,Axin,qcv,out_xt);

    for (int s=0; s<PH; ++s){
      k_fg<<<dim3(16,4,NN),256,0,stream>>>(hb,Axin,Wpack,TI,Sbuf,bhh2F,Cbig);
      k_gru<1><<<dim3(2,BB),256,0,stream>>>(Cbig,Gns,hb);
      k_tg<0><<<dim3(2,4,NN),256,0,stream>>>(Cbig,NC2, Wqcb,512,(size_t)256*512,
          TI, 16, bqcF,256, Cbig,NC2, 512);
      k_out<<<(NN*BB)/4,256,0,stream>>>(Cbig,Gqs,Gcs,TI,flags,P[21],P[22],P[23],P[24],
          qcv,Axin,out_dq,out_cov,s);
    }
  } else {
    // ---- Path B: R11 pipeline (proven) ----
    k_cvt_f<<<(NN*G3+255)/256,256,0,stream>>>(P[11], bihF, NN*G3, flags);
    k_cvt_f<<<(NN*G3+255)/256,256,0,stream>>>(P[12], bhhF, NN*G3, flags);
    k_cvt_wpadg<<<(4*G3*A0S+255)/256,256,0,stream>>>(P[9], Wihb, 4*G3, 328, A0S, flags);
    k_cvt_w<<<(4*G3*512+255)/256,256,0,stream>>>(P[10], Whhb, 4*G3*512, flags);

    k_ngemm<1><<<dim3(HID/8,NN),256,0,stream>>>(Axin,A0S, P[6],328,(size_t)512*328,
        P[7],512, TI,flags, 328, hbuf,512);
    k_mix_init<0><<<dim3(2,BB),256,0,stream>>>(hbuf,G0s,hbuf);
    k_init_state<<<NN,256,0,stream>>>(P[0],P[3],flags,Axin,qcv,out_xt);

    for (int s=0; s<PH; ++s){
      k_mgemm<0,0,0><<<dim3(12,2,NN),256,0,stream>>>(Axin,A0S, Wihb,A0S,(size_t)G3*A0S,
          TI, 11, bihF,G3, Cbig,NC2, 0);
      k_mgemm<1,1,0><<<dim3(12,2,NN),256,0,stream>>>(hbuf,HID, Whhb,512,(size_t)G3*512,
          TI, 16, bhhF,G3, Cbig,NC2, 0);
      k_gru<0><<<dim3(2,BB),256,0,stream>>>(Cbig,Gns,hbuf);
      k_mgemm<0,0,0><<<dim3(2,2,NN),256,0,stream>>>(Cbig,NC2, Wqcb,512,(size_t)256*512,
          TI, 16, bqcF,256, Cbig,NC2, 512);
      k_out<<<(NN*BB)/4,256,0,stream>>>(Cbig,Gqs,Gcs,TI,flags,P[21],P[22],P[23],P[24],
          qcv,Axin,out_dq,out_cov,s);
    }
  }
}